// Round 3
// baseline (815.940 us; speedup 1.0000x reference)
//
#include <hip/hip_runtime.h>

#define NN 100000
#define NE 1600000
#define NG 1024
#define DIN 128
#define D1 100
#define D2 20
#define DSELF 16
#define BN_EPS 1e-5f

typedef unsigned int uint;
typedef unsigned short ushort;

__device__ inline float bflo(uint x) { return __uint_as_float(x << 16); }
__device__ inline float bfhi(uint x) { return __uint_as_float(x & 0xffff0000u); }
__device__ inline uint packbf2(float a, float b) {  // round-nearest-even bf16 pair
    uint ua = __float_as_uint(a), ub = __float_as_uint(b);
    ua += 0x7fffu + ((ua >> 16) & 1u);
    ub += 0x7fffu + ((ub >> 16) & 1u);
    return (ua >> 16) | (ub & 0xffff0000u);
}

// ---------------- transpose g2_W2 only (used by k_m3) ----------------
__global__ void k_prep(const float* __restrict__ W2p, float* __restrict__ W2pT) {
    int id = blockIdx.x * 256 + threadIdx.x;
    if (id < D2 * D2) {
        int k = id / D2, j = id % D2;
        W2pT[j * D2 + k] = W2p[id];
    }
}

// ------- z1bf = bf16(feat @ W1), rows padded to 128 cols (256 B aligned) -----
__global__ __launch_bounds__(256) void k_gemm1(const float* __restrict__ feat,
                                               const float* __restrict__ W1,
                                               ushort* __restrict__ z1bf) {
    __shared__ float As[128 * 65];  // k-major, pad 65 -> 2-way (free)
    int t = threadIdx.x;
    int row0 = blockIdx.x * 64;
#pragma unroll
    for (int i = 0; i < 8; i++) {
        int p = i * 256 + t;   // float4 index
        int r = p >> 5, cq = p & 31;
        int row = row0 + r; if (row >= NN) row = NN - 1;
        float4 v = *(const float4*)(feat + (size_t)row * DIN + cq * 4);
        As[(4 * cq + 0) * 65 + r] = v.x;
        As[(4 * cq + 1) * 65 + r] = v.y;
        As[(4 * cq + 2) * 65 + r] = v.z;
        As[(4 * cq + 3) * 65 + r] = v.w;
    }
    __syncthreads();
    int cg = __builtin_amdgcn_readfirstlane(t >> 6);  // wave-uniform col group
    int r = t & 63;
    int j0 = cg * 25;
    float acc[25];
#pragma unroll
    for (int m = 0; m < 25; m++) acc[m] = 0.f;
    for (int k = 0; k < DIN; k++) {
        float a = As[k * 65 + r];
        const float* wr = W1 + k * D1 + j0;  // wave-uniform -> s_load
#pragma unroll
        for (int m = 0; m < 25; m++) acc[m] = fmaf(a, wr[m], acc[m]);
    }
    __syncthreads();
#pragma unroll
    for (int m = 0; m < 25; m++) As[r * 100 + j0 + m] = acc[m];
    __syncthreads();
#pragma unroll
    for (int i = 0; i < 13; i++) {
        int p = i * 256 + t;          // 3200 ushort2 = 64 rows x 50 pairs
        if (p < 3200) {
            int rr = p / 50, cc = 2 * (p % 50);
            int row = row0 + rr;
            if (row < NN) {
                float v0 = As[rr * 100 + cc], v1 = As[rr * 100 + cc + 1];
                *(uint*)(z1bf + (size_t)row * 128 + cc) = packbf2(v0, v1);
            }
        }
    }
}

// ---------------- CSR build ----------------
__global__ void k_deg(const int* __restrict__ dst, int* __restrict__ deg) {
    int e = blockIdx.x * 256 + threadIdx.x;
    if (e < NE) atomicAdd(&deg[dst[e]], 1);
}

__global__ void k_scan1(const int* __restrict__ deg, int* __restrict__ offs,
                        int* __restrict__ bsum) {
    __shared__ int s[1024];
    int t = threadIdx.x;
    int i = blockIdx.x * 1024 + t;
    int v = (i < NN) ? deg[i] : 0;
    s[t] = v;
    __syncthreads();
    for (int off = 1; off < 1024; off <<= 1) {
        int x = (t >= off) ? s[t - off] : 0;
        __syncthreads();
        s[t] += x;
        __syncthreads();
    }
    if (i < NN) offs[i] = s[t] - v;
    if (t == 1023) bsum[blockIdx.x] = s[t];
}

__global__ void k_scan2(int* __restrict__ bsum) {
    __shared__ int s[128];
    int t = threadIdx.x;
    int v = (t < 98) ? bsum[t] : 0;
    s[t] = v;
    __syncthreads();
    for (int off = 1; off < 128; off <<= 1) {
        int x = (t >= off) ? s[t - off] : 0;
        __syncthreads();
        s[t] += x;
        __syncthreads();
    }
    if (t < 98) bsum[t] = s[t] - v;
}

__global__ void k_scan3(int* __restrict__ offs, const int* __restrict__ bsum) {
    int i = blockIdx.x * 256 + threadIdx.x;
    if (i < NN) offs[i] += bsum[i >> 10];
}

__global__ void k_fill(const int* __restrict__ src, const int* __restrict__ dst,
                       const int* __restrict__ offs, int* __restrict__ fill,
                       int* __restrict__ srcS) {
    int e = blockIdx.x * 256 + threadIdx.x;
    if (e >= NE) return;
    int d = dst[e];
    int slot = offs[d] + atomicAdd(&fill[d], 1);
    srcS[slot] = src[e];
}

// ------- u1 = z1 + gather-sum; bf16 rows (256 B), wave/node, unroll 4 --------
__global__ __launch_bounds__(256) void k_agg1(const ushort* __restrict__ z1bf,
                                              const int* __restrict__ offs,
                                              const int* __restrict__ deg,
                                              const int* __restrict__ srcS,
                                              float* __restrict__ u1) {
    int wq = __builtin_amdgcn_readfirstlane(threadIdx.x >> 6);
    int l = threadIdx.x & 63;
    int n = blockIdx.x * 4 + wq;
    if (n >= NN) return;
    int d = deg[n], base = offs[n];
    bool act = l < 50;
    const ushort* zc = z1bf + 2 * l;
    float a0 = 0.f, a1 = 0.f, b0 = 0.f, b1 = 0.f;
    float c0 = 0.f, c1 = 0.f, e0 = 0.f, e1 = 0.f;
    int i = 0;
    for (; i + 4 <= d; i += 4) {
        int s0 = srcS[base + i],     s1 = srcS[base + i + 1];
        int s2 = srcS[base + i + 2], s3 = srcS[base + i + 3];
        if (act) {
            uint x0 = *(const uint*)(zc + (size_t)s0 * 128);
            uint x1 = *(const uint*)(zc + (size_t)s1 * 128);
            uint x2 = *(const uint*)(zc + (size_t)s2 * 128);
            uint x3 = *(const uint*)(zc + (size_t)s3 * 128);
            a0 += bflo(x0); a1 += bfhi(x0);
            b0 += bflo(x1); b1 += bfhi(x1);
            c0 += bflo(x2); c1 += bfhi(x2);
            e0 += bflo(x3); e1 += bfhi(x3);
        }
    }
    for (; i < d; i++) {
        int s0 = srcS[base + i];
        if (act) {
            uint x0 = *(const uint*)(zc + (size_t)s0 * 128);
            a0 += bflo(x0); a1 += bfhi(x0);
        }
    }
    if (act) {
        uint xs = *(const uint*)(zc + (size_t)n * 128);
        float r0 = (a0 + b0) + (c0 + e0) + bflo(xs);
        float r1 = (a1 + b1) + (c1 + e1) + bfhi(xs);
        *(float2*)(u1 + (size_t)n * D1 + 2 * l) = make_float2(r0, r1);
    }
}

// ---------------- BN stats (train mode, biased var) ----------------
__global__ void k_bnstat100(const float* __restrict__ u, float* __restrict__ bs,
                            float* __restrict__ bq) {
    int c = threadIdx.x;
    if (c >= 100) return;
    int r0 = blockIdx.x * 64;
    int r1 = r0 + 64; if (r1 > NN) r1 = NN;
    float s = 0.f, q = 0.f;
    for (int r = r0; r < r1; r++) {
        float v = u[(size_t)r * 100 + c];
        s += v; q = fmaf(v, v, q);
    }
    atomicAdd(&bs[c], s);
    atomicAdd(&bq[c], q);
}

__global__ void k_bnstat20(const float* __restrict__ u, float* __restrict__ bs,
                           float* __restrict__ bq) {
    int t = threadIdx.x;
    if (t >= 240) return;
    int c = t % 20, sub = t / 20;   // 12 row-stripes
    int r1 = blockIdx.x * 192 + 192; if (r1 > NN) r1 = NN;
    float s = 0.f, q = 0.f;
    for (int r = blockIdx.x * 192 + sub; r < r1; r += 12) {
        float v = u[(size_t)r * 20 + c];
        s += v; q = fmaf(v, v, q);
    }
    atomicAdd(&bs[c], s);
    atomicAdd(&bq[c], q);
}

template <int D>
__global__ void k_bnfin(const float* __restrict__ bsumv, const float* __restrict__ bsq,
                        const float* __restrict__ gamma, const float* __restrict__ beta,
                        float* __restrict__ sc, float* __restrict__ sh) {
    int c = threadIdx.x;
    if (c >= D) return;
    float mean = bsumv[c] * (1.f / NN);
    float var = bsq[c] * (1.f / NN) - mean * mean;
    float inv = rsqrtf(var + BN_EPS);
    float s = gamma[c] * inv;
    sc[c] = s;
    sh[c] = beta[c] - mean * s;
}

// ------ fused: relu(bn1(u1)) @ g1_W2 + b2 -> relu -> @ g2_W1 = z2bf ----------
__global__ __launch_bounds__(256) void k_m2(const float* __restrict__ u1,
                                            const float* __restrict__ sc,
                                            const float* __restrict__ sh,
                                            const float* __restrict__ W2,   // [100][100]
                                            const float* __restrict__ b2,
                                            const float* __restrict__ W1p,  // [100][20]
                                            ushort* __restrict__ z2bf) {
    __shared__ float Xs[100 * 65];  // 26 KB
    int t = threadIdx.x;
    int row0 = blockIdx.x * 64;
#pragma unroll
    for (int i = 0; i < 25; i++) {
        int p = i * 256 + t;
        int r = p / 100, c = p % 100;
        int row = row0 + r; if (row >= NN) row = NN - 1;
        float v = u1[(size_t)row * D1 + c];
        v = fmaxf(v * sc[c] + sh[c], 0.f);
        Xs[c * 65 + r] = v;
    }
    __syncthreads();
    int cg = __builtin_amdgcn_readfirstlane(t >> 6);
    int r = t & 63;
    int j0 = cg * 25;
    float H[25];
#pragma unroll
    for (int m = 0; m < 25; m++) H[m] = 0.f;
    for (int k = 0; k < D1; k++) {
        float a = Xs[k * 65 + r];
        const float* wr = W2 + k * D1 + j0;  // wave-uniform -> s_load
#pragma unroll
        for (int m = 0; m < 25; m++) H[m] = fmaf(a, wr[m], H[m]);
    }
#pragma unroll
    for (int m = 0; m < 25; m++) H[m] = fmaxf(H[m] + b2[j0 + m], 0.f);
    float pz[20];
#pragma unroll
    for (int c = 0; c < 20; c++) pz[c] = 0.f;
#pragma unroll
    for (int m = 0; m < 25; m++) {
        const float* wp = W1p + (j0 + m) * D2;  // wave-uniform -> s_load
#pragma unroll
        for (int c = 0; c < 20; c++) pz[c] = fmaf(H[m], wp[c], pz[c]);
    }
    __syncthreads();
    float* red = Xs;  // 256x20 = 20.5 KB
#pragma unroll
    for (int c = 0; c < 20; c++) red[t * 20 + c] = pz[c];
    __syncthreads();
#pragma unroll
    for (int i = 0; i < 3; i++) {
        int p = i * 256 + t;          // 640 ushort2 = 64 rows x 10 pairs
        if (p < 640) {
            int rr = p / 10, c2 = 2 * (p % 10);
            int row = row0 + rr;
            if (row < NN) {
                float v0 = red[rr * 20 + c2] + red[(64 + rr) * 20 + c2] +
                           red[(128 + rr) * 20 + c2] + red[(192 + rr) * 20 + c2];
                float v1 = red[rr * 20 + c2 + 1] + red[(64 + rr) * 20 + c2 + 1] +
                           red[(128 + rr) * 20 + c2 + 1] + red[(192 + rr) * 20 + c2 + 1];
                *(uint*)(z2bf + (size_t)row * 32 + c2) = packbf2(v0, v1);
            }
        }
    }
}

// ------- u2 = z2 + gather-sum; bf16 rows padded to 32 (64 B, 1 line) ---------
__global__ __launch_bounds__(256) void k_agg2(const ushort* __restrict__ z2bf,
                                              const int* __restrict__ offs,
                                              const int* __restrict__ deg,
                                              const int* __restrict__ srcS,
                                              float* __restrict__ u2) {
    int t = threadIdx.x;
    if (t >= 250) return;
    int n = blockIdx.x * 25 + t / 10;
    if (n >= NN) return;
    int c2 = 2 * (t % 10);
    int d = deg[n], base = offs[n];
    const ushort* zc = z2bf + c2;
    float a0 = 0.f, a1 = 0.f, b0 = 0.f, b1 = 0.f;
    int i = 0;
    for (; i + 2 <= d; i += 2) {
        uint x0 = *(const uint*)(zc + (size_t)srcS[base + i] * 32);
        uint x1 = *(const uint*)(zc + (size_t)srcS[base + i + 1] * 32);
        a0 += bflo(x0); a1 += bfhi(x0);
        b0 += bflo(x1); b1 += bfhi(x1);
    }
    if (i < d) {
        uint x0 = *(const uint*)(zc + (size_t)srcS[base + i] * 32);
        a0 += bflo(x0); a1 += bfhi(x0);
    }
    uint xs = *(const uint*)(zc + (size_t)n * 32);
    *(float2*)(u2 + (size_t)n * D2 + c2) =
        make_float2(a0 + b0 + bflo(xs), a1 + b1 + bfhi(xs));
}

// ------ fused: relu(bn2(u2)) @ g2_W2 + b2 -> relu = h2 ------------
__global__ __launch_bounds__(256) void k_m3(const float* __restrict__ u2,
                                            const float* __restrict__ sc,
                                            const float* __restrict__ sh,
                                            const float* __restrict__ W2pT,
                                            const float* __restrict__ b2p,
                                            float* __restrict__ h2) {
    int row = blockIdx.x * 256 + threadIdx.x;
    if (row >= NN) return;
    float4 y[5];
    const float4* up = (const float4*)(u2 + (size_t)row * D2);
#pragma unroll
    for (int i = 0; i < 5; i++) {
        float4 v = up[i];
        float4 S = *(const float4*)(sc + 4 * i);
        float4 H = *(const float4*)(sh + 4 * i);
        v.x = fmaxf(v.x * S.x + H.x, 0.f);
        v.y = fmaxf(v.y * S.y + H.y, 0.f);
        v.z = fmaxf(v.z * S.z + H.z, 0.f);
        v.w = fmaxf(v.w * S.w + H.w, 0.f);
        y[i] = v;
    }
    float hrow[D2];
#pragma unroll
    for (int j = 0; j < D2; j++) {
        float h = b2p[j];
        const float4* w = (const float4*)(W2pT + j * D2);
#pragma unroll
        for (int kk = 0; kk < 5; kk++) {
            float4 a = y[kk], b = w[kk];
            h += a.x * b.x + a.y * b.y + a.z * b.z + a.w * b.w;
        }
        hrow[j] = fmaxf(h, 0.f);
    }
    float* hr = h2 + (size_t)row * D2;
#pragma unroll
    for (int c = 0; c < D2; c += 4) {
        float4 o; o.x = hrow[c]; o.y = hrow[c + 1]; o.z = hrow[c + 2]; o.w = hrow[c + 3];
        *(float4*)(hr + c) = o;
    }
}

// ---------------- per-graph ranges (node2graph is sorted) ----------------
__global__ void k_starts(const int* __restrict__ n2g, int* __restrict__ starts) {
    int i = blockIdx.x * 256 + threadIdx.x;
    if (i >= NN) return;
    int g = n2g[i];
    if (i == 0) {
        for (int x = 0; x <= g; x++) starts[x] = 0;
    } else {
        int gp = n2g[i - 1];
        for (int x = gp + 1; x <= g; x++) starts[x] = i;
    }
    if (i == NN - 1) {
        for (int x = g + 1; x <= NG; x++) starts[x] = NN;
    }
}

// ---- wave per graph: 60 lanes = 3 row-stripes x 20 cols, shuffle-reduce -----
__global__ __launch_bounds__(256) void k_pool(const float* __restrict__ h2,
                                              const int* __restrict__ starts,
                                              float* __restrict__ hg) {
    int wq = __builtin_amdgcn_readfirstlane(threadIdx.x >> 6);
    int l = threadIdx.x & 63;
    int g = blockIdx.x * 4 + wq;
    if (g >= NG) return;
    int s0 = starts[g], s1 = starts[g + 1];
    float a = 0.f;
    if (l < 60) {
        int rg = l / 20, c = l % 20;
        for (int n = s0 + rg; n < s1; n += 3) a += h2[(size_t)n * D2 + c];
    }
    float v1 = __shfl(a, l + 20, 64);
    float v2 = __shfl(a, l + 40, 64);
    if (l < 20) {
        float cnt = (float)(s1 - s0);
        hg[g * D2 + l] = (a + v1 + v2) / fmaxf(cnt, 1.f);
    }
}

// ---------------- a1 = kron(hg, self_feat) @ fc1_W ----------------
__global__ void k_head1(const float* __restrict__ hg, const float* __restrict__ sf,
                        const float* __restrict__ fc1W, float* __restrict__ a1) {
    int b = blockIdx.x * 8 + threadIdx.x / 32;
    int c = threadIdx.x % 32;
    if (b >= NG) return;
    const float* hgb = hg + b * D2;
    const float* sfb = sf + b * DSELF;
    float acc = 0.f;
    for (int i = 0; i < D2; i++) {
        float hi = hgb[i];
#pragma unroll
        for (int j = 0; j < DSELF; j++)
            acc += hi * sfb[j] * fc1W[(i * DSELF + j) * 32 + c];
    }
    a1[b * 32 + c] = acc;
}

// ---------------- single-block head: bn1->relu->fc2->bn2->relu->fc3 ----------
__global__ __launch_bounds__(1024) void k_head2(
    const float* __restrict__ a1, const float* __restrict__ g1,
    const float* __restrict__ be1, const float* __restrict__ fc2W,
    const float* __restrict__ g2, const float* __restrict__ be2,
    const float* __restrict__ fc3W, const float* __restrict__ fc3b,
    float* __restrict__ out) {
    int t = threadIdx.x;
    int lane = t & 63, w = t >> 6;
    __shared__ float s1[16][32], s2[16][32];
    __shared__ float sc[32], sh[32], sc2[8], sh2[8];
    float x[32];
    const float4* ap = (const float4*)(a1 + t * 32);
#pragma unroll
    for (int i = 0; i < 8; i++) {
        float4 v = ap[i];
        x[4 * i] = v.x; x[4 * i + 1] = v.y; x[4 * i + 2] = v.z; x[4 * i + 3] = v.w;
    }
#pragma unroll
    for (int c = 0; c < 32; c++) {
        float v = x[c], q = v * v;
        for (int o = 32; o > 0; o >>= 1) {
            v += __shfl_down(v, o, 64);
            q += __shfl_down(q, o, 64);
        }
        if (lane == 0) { s1[w][c] = v; s2[w][c] = q; }
    }
    __syncthreads();
    if (t < 32) {
        float s = 0.f, q = 0.f;
        for (int ww = 0; ww < 16; ww++) { s += s1[ww][t]; q += s2[ww][t]; }
        float mean = s * (1.f / NG);
        float var = q * (1.f / NG) - mean * mean;
        float inv = rsqrtf(var + BN_EPS);
        float scl = g1[t] * inv;
        sc[t] = scl;
        sh[t] = be1[t] - mean * scl;
    }
    __syncthreads();
#pragma unroll
    for (int c = 0; c < 32; c++) x[c] = fmaxf(x[c] * sc[c] + sh[c], 0.f);
    float y[8];
#pragma unroll
    for (int p = 0; p < 8; p++) {
        float a = 0.f;
#pragma unroll
        for (int c = 0; c < 32; c++) a += x[c] * fc2W[c * 8 + p];
        y[p] = a;
    }
    __syncthreads();
#pragma unroll
    for (int p = 0; p < 8; p++) {
        float v = y[p], q = v * v;
        for (int o = 32; o > 0; o >>= 1) {
            v += __shfl_down(v, o, 64);
            q += __shfl_down(q, o, 64);
        }
        if (lane == 0) { s1[w][p] = v; s2[w][p] = q; }
    }
    __syncthreads();
    if (t < 8) {
        float s = 0.f, q = 0.f;
        for (int ww = 0; ww < 16; ww++) { s += s1[ww][t]; q += s2[ww][t]; }
        float mean = s * (1.f / NG);
        float var = q * (1.f / NG) - mean * mean;
        float inv = rsqrtf(var + BN_EPS);
        float scl = g2[t] * inv;
        sc2[t] = scl;
        sh2[t] = be2[t] - mean * scl;
    }
    __syncthreads();
    float o = fc3b[0];
#pragma unroll
    for (int p = 0; p < 8; p++) {
        float yy = fmaxf(y[p] * sc2[p] + sh2[p], 0.f);
        o += yy * fc3W[p];
    }
    out[t] = o;
}

extern "C" void kernel_launch(void* const* d_in, const int* in_sizes, int n_in,
                              void* d_out, int out_size, void* d_ws, size_t ws_size,
                              hipStream_t stream) {
    const float* feat    = (const float*)d_in[0];
    const float* sf      = (const float*)d_in[1];
    const int*   esrc    = (const int*)d_in[2];
    const int*   edst    = (const int*)d_in[3];
    const int*   n2g     = (const int*)d_in[4];
    const float* g1W1    = (const float*)d_in[5];
    const float* g1gam   = (const float*)d_in[7];
    const float* g1bet   = (const float*)d_in[8];
    const float* g1W2    = (const float*)d_in[9];
    const float* g1b2    = (const float*)d_in[10];
    const float* g2W1    = (const float*)d_in[11];
    const float* g2gam   = (const float*)d_in[13];
    const float* g2bet   = (const float*)d_in[14];
    const float* g2W2    = (const float*)d_in[15];
    const float* g2b2    = (const float*)d_in[16];
    const float* fc1W    = (const float*)d_in[17];
    const float* hbn1g   = (const float*)d_in[19];
    const float* hbn1b   = (const float*)d_in[20];
    const float* fc2W    = (const float*)d_in[21];
    const float* hbn2g   = (const float*)d_in[23];
    const float* hbn2b   = (const float*)d_in[24];
    const float* fc3W    = (const float*)d_in[25];
    const float* fc3b    = (const float*)d_in[26];
    float* out = (float*)d_out;

    char* w = (char*)d_ws;
    size_t off = 0;
    auto alloc = [&](size_t bytes) -> char* {
        char* p = w + off;
        off += (bytes + 15) & ~(size_t)15;
        return p;
    };
    // region A: z1bf [100k x 128 bf16] = 25.6 MB; after k_agg1 z1bf is dead and
    // the region is re-used as z2bf (6.4 MB) + u2 (8 MB) + h2 (8 MB) = 22.4 MB
    char* regA = alloc((size_t)NN * 128 * 2);
    ushort* z1bf = (ushort*)regA;
    ushort* z2bf = (ushort*)regA;
    float*  u2   = (float*)(regA + 6400000);
    float*  h2   = (float*)(regA + 14400000);
    float* u1 = (float*)alloc((size_t)NN * D1 * 4);  // 40 MB
    char* zero_base = w + off;
    int*   deg   = (int*)alloc(NN * 4);
    int*   fill  = (int*)alloc(NN * 4);
    float* bn1s  = (float*)alloc(D1 * 4);
    float* bn1q  = (float*)alloc(D1 * 4);
    float* bn2s  = (float*)alloc(D2 * 4);
    float* bn2q  = (float*)alloc(D2 * 4);
    size_t zero_sz = (size_t)((w + off) - zero_base);
    int*   offs  = (int*)alloc(NN * 4);
    int*   bsum  = (int*)alloc(128 * 4);
    int*   srcS  = (int*)alloc((size_t)NE * 4);
    int*   starts= (int*)alloc((NG + 1) * 4);
    float* W2pT  = (float*)alloc(D2 * D2 * 4);
    float* sc1   = (float*)alloc(D1 * 4);
    float* sh1   = (float*)alloc(D1 * 4);
    float* sc2   = (float*)alloc(D2 * 4);
    float* sh2   = (float*)alloc(D2 * 4);
    float* hg    = (float*)alloc(NG * D2 * 4);
    float* a1    = (float*)alloc(NG * 32 * 4);
    (void)in_sizes; (void)n_in; (void)out_size; (void)ws_size;

    hipMemsetAsync(zero_base, 0, zero_sz, stream);

    k_prep<<<2, 256, 0, stream>>>(g2W2, W2pT);
    k_gemm1<<<(NN + 63) / 64, 256, 0, stream>>>(feat, g1W1, z1bf);

    k_deg<<<(NE + 255) / 256, 256, 0, stream>>>(edst, deg);
    k_scan1<<<98, 1024, 0, stream>>>(deg, offs, bsum);
    k_scan2<<<1, 128, 0, stream>>>(bsum);
    k_scan3<<<(NN + 255) / 256, 256, 0, stream>>>(offs, bsum);
    k_fill<<<(NE + 255) / 256, 256, 0, stream>>>(esrc, edst, offs, fill, srcS);

    k_agg1<<<(NN + 3) / 4, 256, 0, stream>>>(z1bf, offs, deg, srcS, u1);
    k_bnstat100<<<(NN + 63) / 64, 128, 0, stream>>>(u1, bn1s, bn1q);
    k_bnfin<D1><<<1, 128, 0, stream>>>(bn1s, bn1q, g1gam, g1bet, sc1, sh1);
    k_m2<<<(NN + 63) / 64, 256, 0, stream>>>(u1, sc1, sh1, g1W2, g1b2, g2W1, z2bf);

    k_agg2<<<(NN + 24) / 25, 256, 0, stream>>>(z2bf, offs, deg, srcS, u2);
    k_bnstat20<<<(NN + 191) / 192, 256, 0, stream>>>(u2, bn2s, bn2q);
    k_bnfin<D2><<<1, 128, 0, stream>>>(bn2s, bn2q, g2gam, g2bet, sc2, sh2);
    k_m3<<<(NN + 255) / 256, 256, 0, stream>>>(u2, sc2, sh2, W2pT, g2b2, h2);

    k_starts<<<(NN + 255) / 256, 256, 0, stream>>>(n2g, starts);
    k_pool<<<(NG + 3) / 4, 256, 0, stream>>>(h2, starts, hg);
    k_head1<<<NG / 8, 256, 0, stream>>>(hg, sf, fc1W, a1);
    k_head2<<<1, 1024, 0, stream>>>(a1, hbn1g, hbn1b, fc2W, hbn2g, hbn2b, fc3W, fc3b, out);
}

// Round 4
// 683.922 us; speedup vs baseline: 1.1930x; 1.1930x over previous
//
#include <hip/hip_runtime.h>

#define NN 100000
#define NE 1600000
#define NG 1024
#define DIN 128
#define D1 100
#define D2 20
#define DSELF 16
#define BN_EPS 1e-5f

typedef unsigned int uint;
typedef unsigned short ushort;

__device__ inline float bflo(uint x) { return __uint_as_float(x << 16); }
__device__ inline float bfhi(uint x) { return __uint_as_float(x & 0xffff0000u); }
__device__ inline uint packbf2(float a, float b) {  // round-nearest-even bf16 pair
    uint ua = __float_as_uint(a), ub = __float_as_uint(b);
    ua += 0x7fffu + ((ua >> 16) & 1u);
    ub += 0x7fffu + ((ub >> 16) & 1u);
    return (ua >> 16) | (ub & 0xffff0000u);
}

// ---------------- transpose g2_W2 only (used by k_m3) ----------------
__global__ void k_prep(const float* __restrict__ W2p, float* __restrict__ W2pT) {
    int id = blockIdx.x * 256 + threadIdx.x;
    if (id < D2 * D2) {
        int k = id / D2, j = id % D2;
        W2pT[j * D2 + k] = W2p[id];
    }
}

// ------- z1bf = bf16(feat @ W1), rows padded to 128 cols (256 B aligned) -----
__global__ __launch_bounds__(256) void k_gemm1(const float* __restrict__ feat,
                                               const float* __restrict__ W1,
                                               ushort* __restrict__ z1bf) {
    __shared__ float As[128 * 65];  // k-major, pad 65 -> 2-way (free)
    int t = threadIdx.x;
    int row0 = blockIdx.x * 64;
#pragma unroll
    for (int i = 0; i < 8; i++) {
        int p = i * 256 + t;   // float4 index
        int r = p >> 5, cq = p & 31;
        int row = row0 + r; if (row >= NN) row = NN - 1;
        float4 v = *(const float4*)(feat + (size_t)row * DIN + cq * 4);
        As[(4 * cq + 0) * 65 + r] = v.x;
        As[(4 * cq + 1) * 65 + r] = v.y;
        As[(4 * cq + 2) * 65 + r] = v.z;
        As[(4 * cq + 3) * 65 + r] = v.w;
    }
    __syncthreads();
    int cg = __builtin_amdgcn_readfirstlane(t >> 6);  // wave-uniform col group
    int r = t & 63;
    int j0 = cg * 25;
    float acc[25];
#pragma unroll
    for (int m = 0; m < 25; m++) acc[m] = 0.f;
    for (int k = 0; k < DIN; k++) {
        float a = As[k * 65 + r];
        const float* wr = W1 + k * D1 + j0;  // wave-uniform -> s_load
#pragma unroll
        for (int m = 0; m < 25; m++) acc[m] = fmaf(a, wr[m], acc[m]);
    }
    __syncthreads();
#pragma unroll
    for (int m = 0; m < 25; m++) As[r * 100 + j0 + m] = acc[m];
    __syncthreads();
#pragma unroll
    for (int i = 0; i < 13; i++) {
        int p = i * 256 + t;          // 3200 ushort2 = 64 rows x 50 pairs
        if (p < 3200) {
            int rr = p / 50, cc = 2 * (p % 50);
            int row = row0 + rr;
            if (row < NN) {
                float v0 = As[rr * 100 + cc], v1 = As[rr * 100 + cc + 1];
                *(uint*)(z1bf + (size_t)row * 128 + cc) = packbf2(v0, v1);
            }
        }
    }
}

// ---------------- CSR build ----------------
__global__ void k_deg(const int* __restrict__ dst, int* __restrict__ deg) {
    int e = blockIdx.x * 256 + threadIdx.x;
    if (e < NE) atomicAdd(&deg[dst[e]], 1);
}

__global__ void k_scan1(const int* __restrict__ deg, int* __restrict__ offs,
                        int* __restrict__ bsum) {
    __shared__ int s[1024];
    int t = threadIdx.x;
    int i = blockIdx.x * 1024 + t;
    int v = (i < NN) ? deg[i] : 0;
    s[t] = v;
    __syncthreads();
    for (int off = 1; off < 1024; off <<= 1) {
        int x = (t >= off) ? s[t - off] : 0;
        __syncthreads();
        s[t] += x;
        __syncthreads();
    }
    if (i < NN) offs[i] = s[t] - v;
    if (t == 1023) bsum[blockIdx.x] = s[t];
}

__global__ void k_scan2(int* __restrict__ bsum) {
    __shared__ int s[128];
    int t = threadIdx.x;
    int v = (t < 98) ? bsum[t] : 0;
    s[t] = v;
    __syncthreads();
    for (int off = 1; off < 128; off <<= 1) {
        int x = (t >= off) ? s[t - off] : 0;
        __syncthreads();
        s[t] += x;
        __syncthreads();
    }
    if (t < 98) bsum[t] = s[t] - v;
}

__global__ void k_scan3(int* __restrict__ offs, const int* __restrict__ bsum) {
    int i = blockIdx.x * 256 + threadIdx.x;
    if (i < NN) offs[i] += bsum[i >> 10];
}

__global__ void k_fill(const int* __restrict__ src, const int* __restrict__ dst,
                       const int* __restrict__ offs, int* __restrict__ fill,
                       int* __restrict__ srcS) {
    int e = blockIdx.x * 256 + threadIdx.x;
    if (e >= NE) return;
    int d = dst[e];
    int slot = offs[d] + atomicAdd(&fill[d], 1);
    srcS[slot] = src[e];
}

// ------- u1 = z1 + gather-sum; bf16 rows (256 B), wave/node, unroll 4 --------
__global__ __launch_bounds__(256) void k_agg1(const ushort* __restrict__ z1bf,
                                              const int* __restrict__ offs,
                                              const int* __restrict__ deg,
                                              const int* __restrict__ srcS,
                                              float* __restrict__ u1) {
    int wq = __builtin_amdgcn_readfirstlane(threadIdx.x >> 6);
    int l = threadIdx.x & 63;
    int n = blockIdx.x * 4 + wq;
    if (n >= NN) return;
    int d = deg[n], base = offs[n];
    bool act = l < 50;
    const ushort* zc = z1bf + 2 * l;
    float a0 = 0.f, a1 = 0.f, b0 = 0.f, b1 = 0.f;
    float c0 = 0.f, c1 = 0.f, e0 = 0.f, e1 = 0.f;
    int i = 0;
    for (; i + 4 <= d; i += 4) {
        int s0 = srcS[base + i],     s1 = srcS[base + i + 1];
        int s2 = srcS[base + i + 2], s3 = srcS[base + i + 3];
        if (act) {
            uint x0 = *(const uint*)(zc + (size_t)s0 * 128);
            uint x1 = *(const uint*)(zc + (size_t)s1 * 128);
            uint x2 = *(const uint*)(zc + (size_t)s2 * 128);
            uint x3 = *(const uint*)(zc + (size_t)s3 * 128);
            a0 += bflo(x0); a1 += bfhi(x0);
            b0 += bflo(x1); b1 += bfhi(x1);
            c0 += bflo(x2); c1 += bfhi(x2);
            e0 += bflo(x3); e1 += bfhi(x3);
        }
    }
    for (; i < d; i++) {
        int s0 = srcS[base + i];
        if (act) {
            uint x0 = *(const uint*)(zc + (size_t)s0 * 128);
            a0 += bflo(x0); a1 += bfhi(x0);
        }
    }
    if (act) {
        uint xs = *(const uint*)(zc + (size_t)n * 128);
        float r0 = (a0 + b0) + (c0 + e0) + bflo(xs);
        float r1 = (a1 + b1) + (c1 + e1) + bfhi(xs);
        *(float2*)(u1 + (size_t)n * D1 + 2 * l) = make_float2(r0, r1);
    }
}

// ----- BN stats, hierarchical: per-thread acc -> LDS -> 1 atomic/col/block ---
__global__ __launch_bounds__(256) void k_bnstat100(const float* __restrict__ u,
                                                   float* __restrict__ bs,
                                                   float* __restrict__ bq) {
    __shared__ float ls[200], lq[200];
    int t = threadIdx.x;
    const int rows_per = 782;  // ceil(100000/128)
    int r0 = blockIdx.x * rows_per;
    int r1 = r0 + rows_per; if (r1 > NN) r1 = NN;
    if (t < 200) {
        int c = t % 100, sub = t / 100;
        float s = 0.f, q = 0.f;
        for (int r = r0 + sub; r < r1; r += 2) {
            float v = u[(size_t)r * 100 + c];
            s += v; q = fmaf(v, v, q);
        }
        ls[t] = s; lq[t] = q;
    }
    __syncthreads();
    if (t < 100) {
        atomicAdd(&bs[t], ls[t] + ls[t + 100]);
        atomicAdd(&bq[t], lq[t] + lq[t + 100]);
    }
}

__global__ __launch_bounds__(256) void k_bnstat20(const float* __restrict__ u,
                                                  float* __restrict__ bs,
                                                  float* __restrict__ bq) {
    __shared__ float ls[240], lq[240];
    int t = threadIdx.x;
    const int rows_per = 1563;  // ceil(100000/64)
    int r0 = blockIdx.x * rows_per;
    int r1 = r0 + rows_per; if (r1 > NN) r1 = NN;
    if (t < 240) {
        int c = t % 20, sub = t / 20;  // addr = base + 4*t -> coalesced
        float s = 0.f, q = 0.f;
        for (int r = r0 + sub; r < r1; r += 12) {
            float v = u[(size_t)r * 20 + c];
            s += v; q = fmaf(v, v, q);
        }
        ls[t] = s; lq[t] = q;
    }
    __syncthreads();
    if (t < 20) {
        float S = 0.f, Q = 0.f;
#pragma unroll
        for (int k = 0; k < 12; k++) { S += ls[t + 20 * k]; Q += lq[t + 20 * k]; }
        atomicAdd(&bs[t], S);
        atomicAdd(&bq[t], Q);
    }
}

template <int D>
__global__ void k_bnfin(const float* __restrict__ bsumv, const float* __restrict__ bsq,
                        const float* __restrict__ gamma, const float* __restrict__ beta,
                        float* __restrict__ sc, float* __restrict__ sh) {
    int c = threadIdx.x;
    if (c >= D) return;
    float mean = bsumv[c] * (1.f / NN);
    float var = bsq[c] * (1.f / NN) - mean * mean;
    float inv = rsqrtf(var + BN_EPS);
    float s = gamma[c] * inv;
    sc[c] = s;
    sh[c] = beta[c] - mean * s;
}

// ------ fused: relu(bn1(u1)) @ g1_W2 + b2 -> relu -> @ g2_W1 = z2bf ----------
__global__ __launch_bounds__(256) void k_m2(const float* __restrict__ u1,
                                            const float* __restrict__ sc,
                                            const float* __restrict__ sh,
                                            const float* __restrict__ W2,   // [100][100]
                                            const float* __restrict__ b2,
                                            const float* __restrict__ W1p,  // [100][20]
                                            ushort* __restrict__ z2bf) {
    __shared__ float Xs[100 * 65];  // 26 KB
    int t = threadIdx.x;
    int row0 = blockIdx.x * 64;
#pragma unroll
    for (int i = 0; i < 25; i++) {
        int p = i * 256 + t;
        int r = p / 100, c = p % 100;
        int row = row0 + r; if (row >= NN) row = NN - 1;
        float v = u1[(size_t)row * D1 + c];
        v = fmaxf(v * sc[c] + sh[c], 0.f);
        Xs[c * 65 + r] = v;
    }
    __syncthreads();
    int cg = __builtin_amdgcn_readfirstlane(t >> 6);
    int r = t & 63;
    int j0 = cg * 25;
    float H[25];
#pragma unroll
    for (int m = 0; m < 25; m++) H[m] = 0.f;
    for (int k = 0; k < D1; k++) {
        float a = Xs[k * 65 + r];
        const float* wr = W2 + k * D1 + j0;  // wave-uniform -> s_load
#pragma unroll
        for (int m = 0; m < 25; m++) H[m] = fmaf(a, wr[m], H[m]);
    }
#pragma unroll
    for (int m = 0; m < 25; m++) H[m] = fmaxf(H[m] + b2[j0 + m], 0.f);
    float pz[20];
#pragma unroll
    for (int c = 0; c < 20; c++) pz[c] = 0.f;
#pragma unroll
    for (int m = 0; m < 25; m++) {
        const float* wp = W1p + (j0 + m) * D2;  // wave-uniform -> s_load
#pragma unroll
        for (int c = 0; c < 20; c++) pz[c] = fmaf(H[m], wp[c], pz[c]);
    }
    __syncthreads();
    float* red = Xs;  // 256x20 = 20.5 KB
#pragma unroll
    for (int c = 0; c < 20; c++) red[t * 20 + c] = pz[c];
    __syncthreads();
#pragma unroll
    for (int i = 0; i < 3; i++) {
        int p = i * 256 + t;          // 640 ushort2 = 64 rows x 10 pairs
        if (p < 640) {
            int rr = p / 10, c2 = 2 * (p % 10);
            int row = row0 + rr;
            if (row < NN) {
                float v0 = red[rr * 20 + c2] + red[(64 + rr) * 20 + c2] +
                           red[(128 + rr) * 20 + c2] + red[(192 + rr) * 20 + c2];
                float v1 = red[rr * 20 + c2 + 1] + red[(64 + rr) * 20 + c2 + 1] +
                           red[(128 + rr) * 20 + c2 + 1] + red[(192 + rr) * 20 + c2 + 1];
                *(uint*)(z2bf + (size_t)row * 32 + c2) = packbf2(v0, v1);
            }
        }
    }
}

// ------- u2 = z2 + gather-sum; bf16 rows padded to 32 (64 B, 1 line) ---------
__global__ __launch_bounds__(256) void k_agg2(const ushort* __restrict__ z2bf,
                                              const int* __restrict__ offs,
                                              const int* __restrict__ deg,
                                              const int* __restrict__ srcS,
                                              float* __restrict__ u2) {
    int t = threadIdx.x;
    if (t >= 250) return;
    int n = blockIdx.x * 25 + t / 10;
    if (n >= NN) return;
    int c2 = 2 * (t % 10);
    int d = deg[n], base = offs[n];
    const ushort* zc = z2bf + c2;
    float a0 = 0.f, a1 = 0.f, b0 = 0.f, b1 = 0.f;
    int i = 0;
    for (; i + 2 <= d; i += 2) {
        uint x0 = *(const uint*)(zc + (size_t)srcS[base + i] * 32);
        uint x1 = *(const uint*)(zc + (size_t)srcS[base + i + 1] * 32);
        a0 += bflo(x0); a1 += bfhi(x0);
        b0 += bflo(x1); b1 += bfhi(x1);
    }
    if (i < d) {
        uint x0 = *(const uint*)(zc + (size_t)srcS[base + i] * 32);
        a0 += bflo(x0); a1 += bfhi(x0);
    }
    uint xs = *(const uint*)(zc + (size_t)n * 32);
    *(float2*)(u2 + (size_t)n * D2 + c2) =
        make_float2(a0 + b0 + bflo(xs), a1 + b1 + bfhi(xs));
}

// ------ fused: relu(bn2(u2)) @ g2_W2 + b2 -> relu = h2 ------------
__global__ __launch_bounds__(256) void k_m3(const float* __restrict__ u2,
                                            const float* __restrict__ sc,
                                            const float* __restrict__ sh,
                                            const float* __restrict__ W2pT,
                                            const float* __restrict__ b2p,
                                            float* __restrict__ h2) {
    int row = blockIdx.x * 256 + threadIdx.x;
    if (row >= NN) return;
    float4 y[5];
    const float4* up = (const float4*)(u2 + (size_t)row * D2);
#pragma unroll
    for (int i = 0; i < 5; i++) {
        float4 v = up[i];
        float4 S = *(const float4*)(sc + 4 * i);
        float4 H = *(const float4*)(sh + 4 * i);
        v.x = fmaxf(v.x * S.x + H.x, 0.f);
        v.y = fmaxf(v.y * S.y + H.y, 0.f);
        v.z = fmaxf(v.z * S.z + H.z, 0.f);
        v.w = fmaxf(v.w * S.w + H.w, 0.f);
        y[i] = v;
    }
    float hrow[D2];
#pragma unroll
    for (int j = 0; j < D2; j++) {
        float h = b2p[j];
        const float4* w = (const float4*)(W2pT + j * D2);
#pragma unroll
        for (int kk = 0; kk < 5; kk++) {
            float4 a = y[kk], b = w[kk];
            h += a.x * b.x + a.y * b.y + a.z * b.z + a.w * b.w;
        }
        hrow[j] = fmaxf(h, 0.f);
    }
    float* hr = h2 + (size_t)row * D2;
#pragma unroll
    for (int c = 0; c < D2; c += 4) {
        float4 o; o.x = hrow[c]; o.y = hrow[c + 1]; o.z = hrow[c + 2]; o.w = hrow[c + 3];
        *(float4*)(hr + c) = o;
    }
}

// ---------------- per-graph ranges (node2graph is sorted) ----------------
__global__ void k_starts(const int* __restrict__ n2g, int* __restrict__ starts) {
    int i = blockIdx.x * 256 + threadIdx.x;
    if (i >= NN) return;
    int g = n2g[i];
    if (i == 0) {
        for (int x = 0; x <= g; x++) starts[x] = 0;
    } else {
        int gp = n2g[i - 1];
        for (int x = gp + 1; x <= g; x++) starts[x] = i;
    }
    if (i == NN - 1) {
        for (int x = g + 1; x <= NG; x++) starts[x] = NN;
    }
}

// ---- wave per graph: 60 lanes = 3 row-stripes x 20 cols, shuffle-reduce -----
__global__ __launch_bounds__(256) void k_pool(const float* __restrict__ h2,
                                              const int* __restrict__ starts,
                                              float* __restrict__ hg) {
    int wq = __builtin_amdgcn_readfirstlane(threadIdx.x >> 6);
    int l = threadIdx.x & 63;
    int g = blockIdx.x * 4 + wq;
    if (g >= NG) return;
    int s0 = starts[g], s1 = starts[g + 1];
    float a = 0.f;
    if (l < 60) {
        int rg = l / 20, c = l % 20;
        for (int n = s0 + rg; n < s1; n += 3) a += h2[(size_t)n * D2 + c];
    }
    float v1 = __shfl(a, l + 20, 64);
    float v2 = __shfl(a, l + 40, 64);
    if (l < 20) {
        float cnt = (float)(s1 - s0);
        hg[g * D2 + l] = (a + v1 + v2) / fmaxf(cnt, 1.f);
    }
}

// ---------------- a1 = kron(hg, self_feat) @ fc1_W ----------------
__global__ void k_head1(const float* __restrict__ hg, const float* __restrict__ sf,
                        const float* __restrict__ fc1W, float* __restrict__ a1) {
    int b = blockIdx.x * 8 + threadIdx.x / 32;
    int c = threadIdx.x % 32;
    if (b >= NG) return;
    const float* hgb = hg + b * D2;
    const float* sfb = sf + b * DSELF;
    float acc = 0.f;
    for (int i = 0; i < D2; i++) {
        float hi = hgb[i];
#pragma unroll
        for (int j = 0; j < DSELF; j++)
            acc += hi * sfb[j] * fc1W[(i * DSELF + j) * 32 + c];
    }
    a1[b * 32 + c] = acc;
}

// ---------------- single-block head: bn1->relu->fc2->bn2->relu->fc3 ----------
__global__ __launch_bounds__(1024) void k_head2(
    const float* __restrict__ a1, const float* __restrict__ g1,
    const float* __restrict__ be1, const float* __restrict__ fc2W,
    const float* __restrict__ g2, const float* __restrict__ be2,
    const float* __restrict__ fc3W, const float* __restrict__ fc3b,
    float* __restrict__ out) {
    int t = threadIdx.x;
    int lane = t & 63, w = t >> 6;
    __shared__ float s1[16][32], s2[16][32];
    __shared__ float sc[32], sh[32], sc2[8], sh2[8];
    float x[32];
    const float4* ap = (const float4*)(a1 + t * 32);
#pragma unroll
    for (int i = 0; i < 8; i++) {
        float4 v = ap[i];
        x[4 * i] = v.x; x[4 * i + 1] = v.y; x[4 * i + 2] = v.z; x[4 * i + 3] = v.w;
    }
#pragma unroll
    for (int c = 0; c < 32; c++) {
        float v = x[c], q = v * v;
        for (int o = 32; o > 0; o >>= 1) {
            v += __shfl_down(v, o, 64);
            q += __shfl_down(q, o, 64);
        }
        if (lane == 0) { s1[w][c] = v; s2[w][c] = q; }
    }
    __syncthreads();
    if (t < 32) {
        float s = 0.f, q = 0.f;
        for (int ww = 0; ww < 16; ww++) { s += s1[ww][t]; q += s2[ww][t]; }
        float mean = s * (1.f / NG);
        float var = q * (1.f / NG) - mean * mean;
        float inv = rsqrtf(var + BN_EPS);
        float scl = g1[t] * inv;
        sc[t] = scl;
        sh[t] = be1[t] - mean * scl;
    }
    __syncthreads();
#pragma unroll
    for (int c = 0; c < 32; c++) x[c] = fmaxf(x[c] * sc[c] + sh[c], 0.f);
    float y[8];
#pragma unroll
    for (int p = 0; p < 8; p++) {
        float a = 0.f;
#pragma unroll
        for (int c = 0; c < 32; c++) a += x[c] * fc2W[c * 8 + p];
        y[p] = a;
    }
    __syncthreads();
#pragma unroll
    for (int p = 0; p < 8; p++) {
        float v = y[p], q = v * v;
        for (int o = 32; o > 0; o >>= 1) {
            v += __shfl_down(v, o, 64);
            q += __shfl_down(q, o, 64);
        }
        if (lane == 0) { s1[w][p] = v; s2[w][p] = q; }
    }
    __syncthreads();
    if (t < 8) {
        float s = 0.f, q = 0.f;
        for (int ww = 0; ww < 16; ww++) { s += s1[ww][t]; q += s2[ww][t]; }
        float mean = s * (1.f / NG);
        float var = q * (1.f / NG) - mean * mean;
        float inv = rsqrtf(var + BN_EPS);
        float scl = g2[t] * inv;
        sc2[t] = scl;
        sh2[t] = be2[t] - mean * scl;
    }
    __syncthreads();
    float o = fc3b[0];
#pragma unroll
    for (int p = 0; p < 8; p++) {
        float yy = fmaxf(y[p] * sc2[p] + sh2[p], 0.f);
        o += yy * fc3W[p];
    }
    out[t] = o;
}

extern "C" void kernel_launch(void* const* d_in, const int* in_sizes, int n_in,
                              void* d_out, int out_size, void* d_ws, size_t ws_size,
                              hipStream_t stream) {
    const float* feat    = (const float*)d_in[0];
    const float* sf      = (const float*)d_in[1];
    const int*   esrc    = (const int*)d_in[2];
    const int*   edst    = (const int*)d_in[3];
    const int*   n2g     = (const int*)d_in[4];
    const float* g1W1    = (const float*)d_in[5];
    const float* g1gam   = (const float*)d_in[7];
    const float* g1bet   = (const float*)d_in[8];
    const float* g1W2    = (const float*)d_in[9];
    const float* g1b2    = (const float*)d_in[10];
    const float* g2W1    = (const float*)d_in[11];
    const float* g2gam   = (const float*)d_in[13];
    const float* g2bet   = (const float*)d_in[14];
    const float* g2W2    = (const float*)d_in[15];
    const float* g2b2    = (const float*)d_in[16];
    const float* fc1W    = (const float*)d_in[17];
    const float* hbn1g   = (const float*)d_in[19];
    const float* hbn1b   = (const float*)d_in[20];
    const float* fc2W    = (const float*)d_in[21];
    const float* hbn2g   = (const float*)d_in[23];
    const float* hbn2b   = (const float*)d_in[24];
    const float* fc3W    = (const float*)d_in[25];
    const float* fc3b    = (const float*)d_in[26];
    float* out = (float*)d_out;

    char* w = (char*)d_ws;
    size_t off = 0;
    auto alloc = [&](size_t bytes) -> char* {
        char* p = w + off;
        off += (bytes + 15) & ~(size_t)15;
        return p;
    };
    // region A: z1bf [100k x 128 bf16] = 25.6 MB; after k_agg1 z1bf is dead and
    // the region is re-used as z2bf (6.4 MB) + u2 (8 MB) + h2 (8 MB) = 22.4 MB
    char* regA = alloc((size_t)NN * 128 * 2);
    ushort* z1bf = (ushort*)regA;
    ushort* z2bf = (ushort*)regA;
    float*  u2   = (float*)(regA + 6400000);
    float*  h2   = (float*)(regA + 14400000);
    float* u1 = (float*)alloc((size_t)NN * D1 * 4);  // 40 MB
    char* zero_base = w + off;
    int*   deg   = (int*)alloc(NN * 4);
    int*   fill  = (int*)alloc(NN * 4);
    float* bn1s  = (float*)alloc(D1 * 4);
    float* bn1q  = (float*)alloc(D1 * 4);
    float* bn2s  = (float*)alloc(D2 * 4);
    float* bn2q  = (float*)alloc(D2 * 4);
    size_t zero_sz = (size_t)((w + off) - zero_base);
    int*   offs  = (int*)alloc(NN * 4);
    int*   bsum  = (int*)alloc(128 * 4);
    int*   srcS  = (int*)alloc((size_t)NE * 4);
    int*   starts= (int*)alloc((NG + 1) * 4);
    float* W2pT  = (float*)alloc(D2 * D2 * 4);
    float* sc1   = (float*)alloc(D1 * 4);
    float* sh1   = (float*)alloc(D1 * 4);
    float* sc2   = (float*)alloc(D2 * 4);
    float* sh2   = (float*)alloc(D2 * 4);
    float* hg    = (float*)alloc(NG * D2 * 4);
    float* a1    = (float*)alloc(NG * 32 * 4);
    (void)in_sizes; (void)n_in; (void)out_size; (void)ws_size;

    hipMemsetAsync(zero_base, 0, zero_sz, stream);

    k_prep<<<2, 256, 0, stream>>>(g2W2, W2pT);
    k_gemm1<<<(NN + 63) / 64, 256, 0, stream>>>(feat, g1W1, z1bf);

    k_deg<<<(NE + 255) / 256, 256, 0, stream>>>(edst, deg);
    k_scan1<<<98, 1024, 0, stream>>>(deg, offs, bsum);
    k_scan2<<<1, 128, 0, stream>>>(bsum);
    k_scan3<<<(NN + 255) / 256, 256, 0, stream>>>(offs, bsum);
    k_fill<<<(NE + 255) / 256, 256, 0, stream>>>(esrc, edst, offs, fill, srcS);

    k_agg1<<<(NN + 3) / 4, 256, 0, stream>>>(z1bf, offs, deg, srcS, u1);
    k_bnstat100<<<128, 256, 0, stream>>>(u1, bn1s, bn1q);
    k_bnfin<D1><<<1, 128, 0, stream>>>(bn1s, bn1q, g1gam, g1bet, sc1, sh1);
    k_m2<<<(NN + 63) / 64, 256, 0, stream>>>(u1, sc1, sh1, g1W2, g1b2, g2W1, z2bf);

    k_agg2<<<(NN + 24) / 25, 256, 0, stream>>>(z2bf, offs, deg, srcS, u2);
    k_bnstat20<<<64, 256, 0, stream>>>(u2, bn2s, bn2q);
    k_bnfin<D2><<<1, 128, 0, stream>>>(bn2s, bn2q, g2gam, g2bet, sc2, sh2);
    k_m3<<<(NN + 255) / 256, 256, 0, stream>>>(u2, sc2, sh2, W2pT, g2b2, h2);

    k_starts<<<(NN + 255) / 256, 256, 0, stream>>>(n2g, starts);
    k_pool<<<(NG + 3) / 4, 256, 0, stream>>>(h2, starts, hg);
    k_head1<<<NG / 8, 256, 0, stream>>>(hg, sf, fc1W, a1);
    k_head2<<<1, 1024, 0, stream>>>(a1, hbn1g, hbn1b, fc2W, hbn2g, hbn2b, fc3W, fc3b, out);
}

// Round 5
// 587.983 us; speedup vs baseline: 1.3877x; 1.1632x over previous
//
#include <hip/hip_runtime.h>

#define NN 100000
#define NE 1600000
#define NG 1024
#define DIN 128
#define D1 100
#define D2 20
#define DSELF 16
#define BN_EPS 1e-5f

typedef unsigned int uint;
typedef unsigned short ushort;

__device__ inline float bflo(uint x) { return __uint_as_float(x << 16); }
__device__ inline float bfhi(uint x) { return __uint_as_float(x & 0xffff0000u); }
__device__ inline uint packbf2(float a, float b) {  // round-nearest-even bf16 pair
    uint ua = __float_as_uint(a), ub = __float_as_uint(b);
    ua += 0x7fffu + ((ua >> 16) & 1u);
    ub += 0x7fffu + ((ub >> 16) & 1u);
    return (ua >> 16) | (ub & 0xffff0000u);
}

// ---------------- transpose g2_W2 only (used by k_m3) ----------------
__global__ void k_prep(const float* __restrict__ W2p, float* __restrict__ W2pT) {
    int id = blockIdx.x * 256 + threadIdx.x;
    if (id < D2 * D2) {
        int k = id / D2, j = id % D2;
        W2pT[j * D2 + k] = W2p[id];
    }
}

// ------- z1bf = bf16(feat @ W1), rows padded to 128 cols (256 B aligned) -----
__global__ __launch_bounds__(256) void k_gemm1(const float* __restrict__ feat,
                                               const float* __restrict__ W1,
                                               ushort* __restrict__ z1bf) {
    __shared__ float As[128 * 65];  // k-major, pad 65 -> 2-way (free)
    int t = threadIdx.x;
    int row0 = blockIdx.x * 64;
#pragma unroll
    for (int i = 0; i < 8; i++) {
        int p = i * 256 + t;   // float4 index
        int r = p >> 5, cq = p & 31;
        int row = row0 + r; if (row >= NN) row = NN - 1;
        float4 v = *(const float4*)(feat + (size_t)row * DIN + cq * 4);
        As[(4 * cq + 0) * 65 + r] = v.x;
        As[(4 * cq + 1) * 65 + r] = v.y;
        As[(4 * cq + 2) * 65 + r] = v.z;
        As[(4 * cq + 3) * 65 + r] = v.w;
    }
    __syncthreads();
    int cg = __builtin_amdgcn_readfirstlane(t >> 6);  // wave-uniform col group
    int r = t & 63;
    int j0 = cg * 25;
    float acc[25];
#pragma unroll
    for (int m = 0; m < 25; m++) acc[m] = 0.f;
    for (int k = 0; k < DIN; k++) {
        float a = As[k * 65 + r];
        const float* wr = W1 + k * D1 + j0;  // wave-uniform -> s_load
#pragma unroll
        for (int m = 0; m < 25; m++) acc[m] = fmaf(a, wr[m], acc[m]);
    }
    __syncthreads();
#pragma unroll
    for (int m = 0; m < 25; m++) As[r * 100 + j0 + m] = acc[m];
    __syncthreads();
#pragma unroll
    for (int i = 0; i < 13; i++) {
        int p = i * 256 + t;          // 3200 ushort2 = 64 rows x 50 pairs
        if (p < 3200) {
            int rr = p / 50, cc = 2 * (p % 50);
            int row = row0 + rr;
            if (row < NN) {
                float v0 = As[rr * 100 + cc], v1 = As[rr * 100 + cc + 1];
                *(uint*)(z1bf + (size_t)row * 128 + cc) = packbf2(v0, v1);
            }
        }
    }
}

// ---------------- CSR build ----------------
__global__ void k_deg(const int* __restrict__ dst, int* __restrict__ deg) {
    int e = blockIdx.x * 256 + threadIdx.x;
    if (e < NE) atomicAdd(&deg[dst[e]], 1);
}

__global__ void k_scan1(const int* __restrict__ deg, int* __restrict__ offs,
                        int* __restrict__ bsum) {
    __shared__ int s[1024];
    int t = threadIdx.x;
    int i = blockIdx.x * 1024 + t;
    int v = (i < NN) ? deg[i] : 0;
    s[t] = v;
    __syncthreads();
    for (int off = 1; off < 1024; off <<= 1) {
        int x = (t >= off) ? s[t - off] : 0;
        __syncthreads();
        s[t] += x;
        __syncthreads();
    }
    if (i < NN) offs[i] = s[t] - v;
    if (t == 1023) bsum[blockIdx.x] = s[t];
}

__global__ void k_scan2(int* __restrict__ bsum) {
    __shared__ int s[128];
    int t = threadIdx.x;
    int v = (t < 98) ? bsum[t] : 0;
    s[t] = v;
    __syncthreads();
    for (int off = 1; off < 128; off <<= 1) {
        int x = (t >= off) ? s[t - off] : 0;
        __syncthreads();
        s[t] += x;
        __syncthreads();
    }
    if (t < 98) bsum[t] = s[t] - v;
}

__global__ void k_scan3(int* __restrict__ offs, const int* __restrict__ bsum) {
    int i = blockIdx.x * 256 + threadIdx.x;
    if (i < NN) offs[i] += bsum[i >> 10];
}

// 4 dst-windowed passes (blockIdx.y = pass; x-major dispatch order phases them)
// so srcS scatter-writes land in a ~1.6 MB window that stays L2-resident.
__global__ void k_fill(const int* __restrict__ src, const int* __restrict__ dst,
                       const int* __restrict__ offs, int* __restrict__ fill,
                       int* __restrict__ srcS) {
    int e = blockIdx.x * 256 + threadIdx.x;
    if (e >= NE) return;
    int d = dst[e];
    int lo = blockIdx.y * 25000;
    if (d >= lo && d < lo + 25000) {
        int slot = offs[d] + atomicAdd(&fill[d], 1);
        srcS[slot] = src[e];
    }
}

// ------- u1 = z1 + gather-sum; bf16 rows (256 B), wave/node, unroll 4 --------
__global__ __launch_bounds__(256) void k_agg1(const ushort* __restrict__ z1bf,
                                              const int* __restrict__ offs,
                                              const int* __restrict__ deg,
                                              const int* __restrict__ srcS,
                                              float* __restrict__ u1) {
    int wq = __builtin_amdgcn_readfirstlane(threadIdx.x >> 6);
    int l = threadIdx.x & 63;
    int n = blockIdx.x * 4 + wq;
    if (n >= NN) return;
    int d = deg[n], base = offs[n];
    bool act = l < 50;
    const ushort* zc = z1bf + 2 * l;
    float a0 = 0.f, a1 = 0.f, b0 = 0.f, b1 = 0.f;
    float c0 = 0.f, c1 = 0.f, e0 = 0.f, e1 = 0.f;
    int i = 0;
    for (; i + 4 <= d; i += 4) {
        int s0 = srcS[base + i],     s1 = srcS[base + i + 1];
        int s2 = srcS[base + i + 2], s3 = srcS[base + i + 3];
        if (act) {
            uint x0 = *(const uint*)(zc + (size_t)s0 * 128);
            uint x1 = *(const uint*)(zc + (size_t)s1 * 128);
            uint x2 = *(const uint*)(zc + (size_t)s2 * 128);
            uint x3 = *(const uint*)(zc + (size_t)s3 * 128);
            a0 += bflo(x0); a1 += bfhi(x0);
            b0 += bflo(x1); b1 += bfhi(x1);
            c0 += bflo(x2); c1 += bfhi(x2);
            e0 += bflo(x3); e1 += bfhi(x3);
        }
    }
    for (; i < d; i++) {
        int s0 = srcS[base + i];
        if (act) {
            uint x0 = *(const uint*)(zc + (size_t)s0 * 128);
            a0 += bflo(x0); a1 += bfhi(x0);
        }
    }
    if (act) {
        uint xs = *(const uint*)(zc + (size_t)n * 128);
        float r0 = (a0 + b0) + (c0 + e0) + bflo(xs);
        float r1 = (a1 + b1) + (c1 + e1) + bfhi(xs);
        *(float2*)(u1 + (size_t)n * D1 + 2 * l) = make_float2(r0, r1);
    }
}

// ----- BN stats, two-stage (no atomics): blocks write partials, 1 block folds
__global__ __launch_bounds__(256) void k_bnstat100(const float* __restrict__ u,
                                                   float* __restrict__ pb) {
    __shared__ float ls[10][100], lq[10][100];
    int t = threadIdx.x;
    int r0 = blockIdx.x * 200;           // 500 blocks x 200 rows = 100000
    int r1 = r0 + 200; if (r1 > NN) r1 = NN;
    if (t < 250) {
        int sub = t / 25, q = t % 25;
        float4 S = make_float4(0, 0, 0, 0), Q = make_float4(0, 0, 0, 0);
        for (int r = r0 + sub; r < r1; r += 10) {
            float4 v = *(const float4*)(u + (size_t)r * 100 + 4 * q);
            S.x += v.x; S.y += v.y; S.z += v.z; S.w += v.w;
            Q.x = fmaf(v.x, v.x, Q.x); Q.y = fmaf(v.y, v.y, Q.y);
            Q.z = fmaf(v.z, v.z, Q.z); Q.w = fmaf(v.w, v.w, Q.w);
        }
        ls[sub][4 * q + 0] = S.x; ls[sub][4 * q + 1] = S.y;
        ls[sub][4 * q + 2] = S.z; ls[sub][4 * q + 3] = S.w;
        lq[sub][4 * q + 0] = Q.x; lq[sub][4 * q + 1] = Q.y;
        lq[sub][4 * q + 2] = Q.z; lq[sub][4 * q + 3] = Q.w;
    }
    __syncthreads();
    if (t < 100) {
        float S = 0.f, Q = 0.f;
#pragma unroll
        for (int s = 0; s < 10; s++) { S += ls[s][t]; Q += lq[s][t]; }
        pb[blockIdx.x * 200 + t] = S;
        pb[blockIdx.x * 200 + 100 + t] = Q;
    }
}

__global__ __launch_bounds__(512) void k_bnfin100(const float* __restrict__ pb,
                                                  const float* __restrict__ gamma,
                                                  const float* __restrict__ beta,
                                                  float* __restrict__ sc,
                                                  float* __restrict__ sh) {
    __shared__ float ls[4][100], lq[4][100];
    int t = threadIdx.x;
    if (t < 400) {
        int sub = t / 100, c = t % 100;
        float S = 0.f, Q = 0.f;
        for (int b = sub; b < 500; b += 4) {
            S += pb[b * 200 + c];
            Q += pb[b * 200 + 100 + c];
        }
        ls[sub][c] = S; lq[sub][c] = Q;
    }
    __syncthreads();
    if (t < 100) {
        float S = ls[0][t] + ls[1][t] + ls[2][t] + ls[3][t];
        float Q = lq[0][t] + lq[1][t] + lq[2][t] + lq[3][t];
        float mean = S * (1.f / NN);
        float var = Q * (1.f / NN) - mean * mean;
        float inv = rsqrtf(var + BN_EPS);
        float s = gamma[t] * inv;
        sc[t] = s;
        sh[t] = beta[t] - mean * s;
    }
}

__global__ __launch_bounds__(256) void k_bnstat20(const float* __restrict__ u,
                                                  float* __restrict__ pb) {
    __shared__ float ls[50][20], lq[50][20];
    int t = threadIdx.x;
    int r0 = blockIdx.x * 400;           // 250 blocks x 400 rows = 100000
    int r1 = r0 + 400; if (r1 > NN) r1 = NN;
    if (t < 250) {
        int sub = t / 5, q = t % 5;
        float4 S = make_float4(0, 0, 0, 0), Q = make_float4(0, 0, 0, 0);
        for (int r = r0 + sub; r < r1; r += 50) {
            float4 v = *(const float4*)(u + (size_t)r * 20 + 4 * q);
            S.x += v.x; S.y += v.y; S.z += v.z; S.w += v.w;
            Q.x = fmaf(v.x, v.x, Q.x); Q.y = fmaf(v.y, v.y, Q.y);
            Q.z = fmaf(v.z, v.z, Q.z); Q.w = fmaf(v.w, v.w, Q.w);
        }
        ls[sub][4 * q + 0] = S.x; ls[sub][4 * q + 1] = S.y;
        ls[sub][4 * q + 2] = S.z; ls[sub][4 * q + 3] = S.w;
        lq[sub][4 * q + 0] = Q.x; lq[sub][4 * q + 1] = Q.y;
        lq[sub][4 * q + 2] = Q.z; lq[sub][4 * q + 3] = Q.w;
    }
    __syncthreads();
    if (t < 20) {
        float S = 0.f, Q = 0.f;
#pragma unroll
        for (int s = 0; s < 50; s++) { S += ls[s][t]; Q += lq[s][t]; }
        pb[blockIdx.x * 40 + t] = S;
        pb[blockIdx.x * 40 + 20 + t] = Q;
    }
}

__global__ __launch_bounds__(512) void k_bnfin20(const float* __restrict__ pb,
                                                 const float* __restrict__ gamma,
                                                 const float* __restrict__ beta,
                                                 float* __restrict__ sc,
                                                 float* __restrict__ sh) {
    __shared__ float ls[25][20], lq[25][20];
    int t = threadIdx.x;
    if (t < 500) {
        int sub = t / 20, c = t % 20;
        float S = 0.f, Q = 0.f;
        for (int b = sub; b < 250; b += 25) {
            S += pb[b * 40 + c];
            Q += pb[b * 40 + 20 + c];
        }
        ls[sub][c] = S; lq[sub][c] = Q;
    }
    __syncthreads();
    if (t < 20) {
        float S = 0.f, Q = 0.f;
#pragma unroll
        for (int s = 0; s < 25; s++) { S += ls[s][t]; Q += lq[s][t]; }
        float mean = S * (1.f / NN);
        float var = Q * (1.f / NN) - mean * mean;
        float inv = rsqrtf(var + BN_EPS);
        float s = gamma[t] * inv;
        sc[t] = s;
        sh[t] = beta[t] - mean * s;
    }
}

// ------ fused: relu(bn1(u1)) @ g1_W2 + b2 -> relu -> @ g2_W1 = z2bf ----------
__global__ __launch_bounds__(256) void k_m2(const float* __restrict__ u1,
                                            const float* __restrict__ sc,
                                            const float* __restrict__ sh,
                                            const float* __restrict__ W2,   // [100][100]
                                            const float* __restrict__ b2,
                                            const float* __restrict__ W1p,  // [100][20]
                                            ushort* __restrict__ z2bf) {
    __shared__ float Xs[100 * 65];  // 26 KB
    int t = threadIdx.x;
    int row0 = blockIdx.x * 64;
#pragma unroll
    for (int i = 0; i < 25; i++) {
        int p = i * 256 + t;
        int r = p / 100, c = p % 100;
        int row = row0 + r; if (row >= NN) row = NN - 1;
        float v = u1[(size_t)row * D1 + c];
        v = fmaxf(v * sc[c] + sh[c], 0.f);
        Xs[c * 65 + r] = v;
    }
    __syncthreads();
    int cg = __builtin_amdgcn_readfirstlane(t >> 6);
    int r = t & 63;
    int j0 = cg * 25;
    float H[25];
#pragma unroll
    for (int m = 0; m < 25; m++) H[m] = 0.f;
    for (int k = 0; k < D1; k++) {
        float a = Xs[k * 65 + r];
        const float* wr = W2 + k * D1 + j0;  // wave-uniform -> s_load
#pragma unroll
        for (int m = 0; m < 25; m++) H[m] = fmaf(a, wr[m], H[m]);
    }
#pragma unroll
    for (int m = 0; m < 25; m++) H[m] = fmaxf(H[m] + b2[j0 + m], 0.f);
    float pz[20];
#pragma unroll
    for (int c = 0; c < 20; c++) pz[c] = 0.f;
#pragma unroll
    for (int m = 0; m < 25; m++) {
        const float* wp = W1p + (j0 + m) * D2;  // wave-uniform -> s_load
#pragma unroll
        for (int c = 0; c < 20; c++) pz[c] = fmaf(H[m], wp[c], pz[c]);
    }
    __syncthreads();
    float* red = Xs;  // 256x20 = 20.5 KB
#pragma unroll
    for (int c = 0; c < 20; c++) red[t * 20 + c] = pz[c];
    __syncthreads();
#pragma unroll
    for (int i = 0; i < 3; i++) {
        int p = i * 256 + t;          // 640 ushort2 = 64 rows x 10 pairs
        if (p < 640) {
            int rr = p / 10, c2 = 2 * (p % 10);
            int row = row0 + rr;
            if (row < NN) {
                float v0 = red[rr * 20 + c2] + red[(64 + rr) * 20 + c2] +
                           red[(128 + rr) * 20 + c2] + red[(192 + rr) * 20 + c2];
                float v1 = red[rr * 20 + c2 + 1] + red[(64 + rr) * 20 + c2 + 1] +
                           red[(128 + rr) * 20 + c2 + 1] + red[(192 + rr) * 20 + c2 + 1];
                *(uint*)(z2bf + (size_t)row * 32 + c2) = packbf2(v0, v1);
            }
        }
    }
}

// ------- u2 = z2 + gather-sum; bf16 rows padded to 32 (64 B, 1 line) ---------
__global__ __launch_bounds__(256) void k_agg2(const ushort* __restrict__ z2bf,
                                              const int* __restrict__ offs,
                                              const int* __restrict__ deg,
                                              const int* __restrict__ srcS,
                                              float* __restrict__ u2) {
    int t = threadIdx.x;
    if (t >= 250) return;
    int n = blockIdx.x * 25 + t / 10;
    if (n >= NN) return;
    int c2 = 2 * (t % 10);
    int d = deg[n], base = offs[n];
    const ushort* zc = z2bf + c2;
    float a0 = 0.f, a1 = 0.f, b0 = 0.f, b1 = 0.f;
    int i = 0;
    for (; i + 2 <= d; i += 2) {
        uint x0 = *(const uint*)(zc + (size_t)srcS[base + i] * 32);
        uint x1 = *(const uint*)(zc + (size_t)srcS[base + i + 1] * 32);
        a0 += bflo(x0); a1 += bfhi(x0);
        b0 += bflo(x1); b1 += bfhi(x1);
    }
    if (i < d) {
        uint x0 = *(const uint*)(zc + (size_t)srcS[base + i] * 32);
        a0 += bflo(x0); a1 += bfhi(x0);
    }
    uint xs = *(const uint*)(zc + (size_t)n * 32);
    *(float2*)(u2 + (size_t)n * D2 + c2) =
        make_float2(a0 + b0 + bflo(xs), a1 + b1 + bfhi(xs));
}

// ------ fused: relu(bn2(u2)) @ g2_W2 + b2 -> relu = h2 ------------
__global__ __launch_bounds__(256) void k_m3(const float* __restrict__ u2,
                                            const float* __restrict__ sc,
                                            const float* __restrict__ sh,
                                            const float* __restrict__ W2pT,
                                            const float* __restrict__ b2p,
                                            float* __restrict__ h2) {
    int row = blockIdx.x * 256 + threadIdx.x;
    if (row >= NN) return;
    float4 y[5];
    const float4* up = (const float4*)(u2 + (size_t)row * D2);
#pragma unroll
    for (int i = 0; i < 5; i++) {
        float4 v = up[i];
        float4 S = *(const float4*)(sc + 4 * i);
        float4 H = *(const float4*)(sh + 4 * i);
        v.x = fmaxf(v.x * S.x + H.x, 0.f);
        v.y = fmaxf(v.y * S.y + H.y, 0.f);
        v.z = fmaxf(v.z * S.z + H.z, 0.f);
        v.w = fmaxf(v.w * S.w + H.w, 0.f);
        y[i] = v;
    }
    float hrow[D2];
#pragma unroll
    for (int j = 0; j < D2; j++) {
        float h = b2p[j];
        const float4* w = (const float4*)(W2pT + j * D2);
#pragma unroll
        for (int kk = 0; kk < 5; kk++) {
            float4 a = y[kk], b = w[kk];
            h += a.x * b.x + a.y * b.y + a.z * b.z + a.w * b.w;
        }
        hrow[j] = fmaxf(h, 0.f);
    }
    float* hr = h2 + (size_t)row * D2;
#pragma unroll
    for (int c = 0; c < D2; c += 4) {
        float4 o; o.x = hrow[c]; o.y = hrow[c + 1]; o.z = hrow[c + 2]; o.w = hrow[c + 3];
        *(float4*)(hr + c) = o;
    }
}

// ---------------- per-graph ranges (node2graph is sorted) ----------------
__global__ void k_starts(const int* __restrict__ n2g, int* __restrict__ starts) {
    int i = blockIdx.x * 256 + threadIdx.x;
    if (i >= NN) return;
    int g = n2g[i];
    if (i == 0) {
        for (int x = 0; x <= g; x++) starts[x] = 0;
    } else {
        int gp = n2g[i - 1];
        for (int x = gp + 1; x <= g; x++) starts[x] = i;
    }
    if (i == NN - 1) {
        for (int x = g + 1; x <= NG; x++) starts[x] = NN;
    }
}

// ---- wave per graph: 60 lanes = 3 row-stripes x 20 cols, shuffle-reduce -----
__global__ __launch_bounds__(256) void k_pool(const float* __restrict__ h2,
                                              const int* __restrict__ starts,
                                              float* __restrict__ hg) {
    int wq = __builtin_amdgcn_readfirstlane(threadIdx.x >> 6);
    int l = threadIdx.x & 63;
    int g = blockIdx.x * 4 + wq;
    if (g >= NG) return;
    int s0 = starts[g], s1 = starts[g + 1];
    float a = 0.f;
    if (l < 60) {
        int rg = l / 20, c = l % 20;
        for (int n = s0 + rg; n < s1; n += 3) a += h2[(size_t)n * D2 + c];
    }
    float v1 = __shfl(a, l + 20, 64);
    float v2 = __shfl(a, l + 40, 64);
    if (l < 20) {
        float cnt = (float)(s1 - s0);
        hg[g * D2 + l] = (a + v1 + v2) / fmaxf(cnt, 1.f);
    }
}

// ---------------- a1 = kron(hg, self_feat) @ fc1_W ----------------
__global__ void k_head1(const float* __restrict__ hg, const float* __restrict__ sf,
                        const float* __restrict__ fc1W, float* __restrict__ a1) {
    int b = blockIdx.x * 8 + threadIdx.x / 32;
    int c = threadIdx.x % 32;
    if (b >= NG) return;
    const float* hgb = hg + b * D2;
    const float* sfb = sf + b * DSELF;
    float acc = 0.f;
    for (int i = 0; i < D2; i++) {
        float hi = hgb[i];
#pragma unroll
        for (int j = 0; j < DSELF; j++)
            acc += hi * sfb[j] * fc1W[(i * DSELF + j) * 32 + c];
    }
    a1[b * 32 + c] = acc;
}

// ---------------- single-block head: bn1->relu->fc2->bn2->relu->fc3 ----------
__global__ __launch_bounds__(1024) void k_head2(
    const float* __restrict__ a1, const float* __restrict__ g1,
    const float* __restrict__ be1, const float* __restrict__ fc2W,
    const float* __restrict__ g2, const float* __restrict__ be2,
    const float* __restrict__ fc3W, const float* __restrict__ fc3b,
    float* __restrict__ out) {
    int t = threadIdx.x;
    int lane = t & 63, w = t >> 6;
    __shared__ float s1[16][32], s2[16][32];
    __shared__ float sc[32], sh[32], sc2[8], sh2[8];
    float x[32];
    const float4* ap = (const float4*)(a1 + t * 32);
#pragma unroll
    for (int i = 0; i < 8; i++) {
        float4 v = ap[i];
        x[4 * i] = v.x; x[4 * i + 1] = v.y; x[4 * i + 2] = v.z; x[4 * i + 3] = v.w;
    }
#pragma unroll
    for (int c = 0; c < 32; c++) {
        float v = x[c], q = v * v;
        for (int o = 32; o > 0; o >>= 1) {
            v += __shfl_down(v, o, 64);
            q += __shfl_down(q, o, 64);
        }
        if (lane == 0) { s1[w][c] = v; s2[w][c] = q; }
    }
    __syncthreads();
    if (t < 32) {
        float s = 0.f, q = 0.f;
        for (int ww = 0; ww < 16; ww++) { s += s1[ww][t]; q += s2[ww][t]; }
        float mean = s * (1.f / NG);
        float var = q * (1.f / NG) - mean * mean;
        float inv = rsqrtf(var + BN_EPS);
        float scl = g1[t] * inv;
        sc[t] = scl;
        sh[t] = be1[t] - mean * scl;
    }
    __syncthreads();
#pragma unroll
    for (int c = 0; c < 32; c++) x[c] = fmaxf(x[c] * sc[c] + sh[c], 0.f);
    float y[8];
#pragma unroll
    for (int p = 0; p < 8; p++) {
        float a = 0.f;
#pragma unroll
        for (int c = 0; c < 32; c++) a += x[c] * fc2W[c * 8 + p];
        y[p] = a;
    }
    __syncthreads();
#pragma unroll
    for (int p = 0; p < 8; p++) {
        float v = y[p], q = v * v;
        for (int o = 32; o > 0; o >>= 1) {
            v += __shfl_down(v, o, 64);
            q += __shfl_down(q, o, 64);
        }
        if (lane == 0) { s1[w][p] = v; s2[w][p] = q; }
    }
    __syncthreads();
    if (t < 8) {
        float s = 0.f, q = 0.f;
        for (int ww = 0; ww < 16; ww++) { s += s1[ww][t]; q += s2[ww][t]; }
        float mean = s * (1.f / NG);
        float var = q * (1.f / NG) - mean * mean;
        float inv = rsqrtf(var + BN_EPS);
        float scl = g2[t] * inv;
        sc2[t] = scl;
        sh2[t] = be2[t] - mean * scl;
    }
    __syncthreads();
    float o = fc3b[0];
#pragma unroll
    for (int p = 0; p < 8; p++) {
        float yy = fmaxf(y[p] * sc2[p] + sh2[p], 0.f);
        o += yy * fc3W[p];
    }
    out[t] = o;
}

extern "C" void kernel_launch(void* const* d_in, const int* in_sizes, int n_in,
                              void* d_out, int out_size, void* d_ws, size_t ws_size,
                              hipStream_t stream) {
    const float* feat    = (const float*)d_in[0];
    const float* sf      = (const float*)d_in[1];
    const int*   esrc    = (const int*)d_in[2];
    const int*   edst    = (const int*)d_in[3];
    const int*   n2g     = (const int*)d_in[4];
    const float* g1W1    = (const float*)d_in[5];
    const float* g1gam   = (const float*)d_in[7];
    const float* g1bet   = (const float*)d_in[8];
    const float* g1W2    = (const float*)d_in[9];
    const float* g1b2    = (const float*)d_in[10];
    const float* g2W1    = (const float*)d_in[11];
    const float* g2gam   = (const float*)d_in[13];
    const float* g2bet   = (const float*)d_in[14];
    const float* g2W2    = (const float*)d_in[15];
    const float* g2b2    = (const float*)d_in[16];
    const float* fc1W    = (const float*)d_in[17];
    const float* hbn1g   = (const float*)d_in[19];
    const float* hbn1b   = (const float*)d_in[20];
    const float* fc2W    = (const float*)d_in[21];
    const float* hbn2g   = (const float*)d_in[23];
    const float* hbn2b   = (const float*)d_in[24];
    const float* fc3W    = (const float*)d_in[25];
    const float* fc3b    = (const float*)d_in[26];
    float* out = (float*)d_out;

    char* w = (char*)d_ws;
    size_t off = 0;
    auto alloc = [&](size_t bytes) -> char* {
        char* p = w + off;
        off += (bytes + 15) & ~(size_t)15;
        return p;
    };
    // region A: z1bf [100k x 128 bf16] = 25.6 MB; after k_agg1 z1bf is dead and
    // the region is re-used as z2bf (6.4 MB) + u2 (8 MB) + h2 (8 MB) = 22.4 MB
    char* regA = alloc((size_t)NN * 128 * 2);
    ushort* z1bf = (ushort*)regA;
    ushort* z2bf = (ushort*)regA;
    float*  u2   = (float*)(regA + 6400000);
    float*  h2   = (float*)(regA + 14400000);
    float* u1 = (float*)alloc((size_t)NN * D1 * 4);  // 40 MB
    char* zero_base = w + off;
    int*   deg   = (int*)alloc(NN * 4);
    int*   fill  = (int*)alloc(NN * 4);
    size_t zero_sz = (size_t)((w + off) - zero_base);
    int*   offs  = (int*)alloc(NN * 4);
    int*   bsum  = (int*)alloc(128 * 4);
    int*   srcS  = (int*)alloc((size_t)NE * 4);
    int*   starts= (int*)alloc((NG + 1) * 4);
    float* W2pT  = (float*)alloc(D2 * D2 * 4);
    float* pb1   = (float*)alloc(500 * 200 * 4);   // bnstat100 partials
    float* pb2   = (float*)alloc(250 * 40 * 4);    // bnstat20 partials
    float* sc1   = (float*)alloc(D1 * 4);
    float* sh1   = (float*)alloc(D1 * 4);
    float* sc2   = (float*)alloc(D2 * 4);
    float* sh2   = (float*)alloc(D2 * 4);
    float* hg    = (float*)alloc(NG * D2 * 4);
    float* a1    = (float*)alloc(NG * 32 * 4);
    (void)in_sizes; (void)n_in; (void)out_size; (void)ws_size;

    hipMemsetAsync(zero_base, 0, zero_sz, stream);

    k_prep<<<2, 256, 0, stream>>>(g2W2, W2pT);
    k_gemm1<<<(NN + 63) / 64, 256, 0, stream>>>(feat, g1W1, z1bf);

    k_deg<<<(NE + 255) / 256, 256, 0, stream>>>(edst, deg);
    k_scan1<<<98, 1024, 0, stream>>>(deg, offs, bsum);
    k_scan2<<<1, 128, 0, stream>>>(bsum);
    k_scan3<<<(NN + 255) / 256, 256, 0, stream>>>(offs, bsum);
    k_fill<<<dim3((NE + 255) / 256, 4), 256, 0, stream>>>(esrc, edst, offs, fill, srcS);

    k_agg1<<<(NN + 3) / 4, 256, 0, stream>>>(z1bf, offs, deg, srcS, u1);
    k_bnstat100<<<500, 256, 0, stream>>>(u1, pb1);
    k_bnfin100<<<1, 512, 0, stream>>>(pb1, g1gam, g1bet, sc1, sh1);
    k_m2<<<(NN + 63) / 64, 256, 0, stream>>>(u1, sc1, sh1, g1W2, g1b2, g2W1, z2bf);

    k_agg2<<<(NN + 24) / 25, 256, 0, stream>>>(z2bf, offs, deg, srcS, u2);
    k_bnstat20<<<250, 256, 0, stream>>>(u2, pb2);
    k_bnfin20<<<1, 512, 0, stream>>>(pb2, g2gam, g2bet, sc2, sh2);
    k_m3<<<(NN + 255) / 256, 256, 0, stream>>>(u2, sc2, sh2, W2pT, g2b2, h2);

    k_starts<<<(NN + 255) / 256, 256, 0, stream>>>(n2g, starts);
    k_pool<<<(NG + 3) / 4, 256, 0, stream>>>(h2, starts, hg);
    k_head1<<<NG / 8, 256, 0, stream>>>(hg, sf, fc1W, a1);
    k_head2<<<1, 1024, 0, stream>>>(a1, hbn1g, hbn1b, fc2W, hbn2g, hbn2b, fc3W, fc3b, out);
}

// Round 6
// 587.514 us; speedup vs baseline: 1.3888x; 1.0008x over previous
//
#include <hip/hip_runtime.h>

#define NN 100000
#define NE 1600000
#define NG 1024
#define DIN 128
#define D1 100
#define D2 20
#define DSELF 16
#define BN_EPS 1e-5f

typedef unsigned int uint;
typedef unsigned short ushort;

__device__ inline float bflo(uint x) { return __uint_as_float(x << 16); }
__device__ inline float bfhi(uint x) { return __uint_as_float(x & 0xffff0000u); }
__device__ inline uint packbf2(float a, float b) {  // round-nearest-even bf16 pair
    uint ua = __float_as_uint(a), ub = __float_as_uint(b);
    ua += 0x7fffu + ((ua >> 16) & 1u);
    ub += 0x7fffu + ((ub >> 16) & 1u);
    return (ua >> 16) | (ub & 0xffff0000u);
}

// ---------------- transpose g2_W2 only (used by k_m3) ----------------
__global__ void k_prep(const float* __restrict__ W2p, float* __restrict__ W2pT) {
    int id = blockIdx.x * 256 + threadIdx.x;
    if (id < D2 * D2) {
        int k = id / D2, j = id % D2;
        W2pT[j * D2 + k] = W2p[id];
    }
}

// ------- z1bf = bf16(feat @ W1), rows padded to 128 cols (256 B aligned) -----
__global__ __launch_bounds__(256) void k_gemm1(const float* __restrict__ feat,
                                               const float* __restrict__ W1,
                                               ushort* __restrict__ z1bf) {
    __shared__ float As[128 * 65];  // k-major, pad 65 -> 2-way (free)
    int t = threadIdx.x;
    int row0 = blockIdx.x * 64;
#pragma unroll
    for (int i = 0; i < 8; i++) {
        int p = i * 256 + t;   // float4 index
        int r = p >> 5, cq = p & 31;
        int row = row0 + r; if (row >= NN) row = NN - 1;
        float4 v = *(const float4*)(feat + (size_t)row * DIN + cq * 4);
        As[(4 * cq + 0) * 65 + r] = v.x;
        As[(4 * cq + 1) * 65 + r] = v.y;
        As[(4 * cq + 2) * 65 + r] = v.z;
        As[(4 * cq + 3) * 65 + r] = v.w;
    }
    __syncthreads();
    int cg = __builtin_amdgcn_readfirstlane(t >> 6);  // wave-uniform col group
    int r = t & 63;
    int j0 = cg * 25;
    float acc[25];
#pragma unroll
    for (int m = 0; m < 25; m++) acc[m] = 0.f;
    for (int k = 0; k < DIN; k++) {
        float a = As[k * 65 + r];
        const float* wr = W1 + k * D1 + j0;  // wave-uniform -> s_load
#pragma unroll
        for (int m = 0; m < 25; m++) acc[m] = fmaf(a, wr[m], acc[m]);
    }
    __syncthreads();
#pragma unroll
    for (int m = 0; m < 25; m++) As[r * 100 + j0 + m] = acc[m];
    __syncthreads();
#pragma unroll
    for (int i = 0; i < 13; i++) {
        int p = i * 256 + t;          // 3200 ushort2 = 64 rows x 50 pairs
        if (p < 3200) {
            int rr = p / 50, cc = 2 * (p % 50);
            int row = row0 + rr;
            if (row < NN) {
                float v0 = As[rr * 100 + cc], v1 = As[rr * 100 + cc + 1];
                *(uint*)(z1bf + (size_t)row * 128 + cc) = packbf2(v0, v1);
            }
        }
    }
}

// ------------- CSR build: XCD-affine windows (blockIdx.x % 8 = window) -------
// Window w covers nodes [12500*w, 12500*(w+1)). Blocks with x%8==w co-reside
// on one XCD (round-robin dispatch heuristic) so deg/fill/srcS lines for that
// window are dirtied in a single L2 -> single writeback.
__global__ __launch_bounds__(256) void k_deg(const int* __restrict__ dst,
                                             int* __restrict__ deg) {
    int w = blockIdx.x & 7;
    int s = blockIdx.x >> 3;
    int lo = w * 12500, hi = lo + 12500;
    int e0 = s * 2048 + threadIdx.x;
#pragma unroll
    for (int i = 0; i < 8; i++) {
        int e = e0 + i * 256;
        if (e < NE) {
            int d = dst[e];
            if (d >= lo && d < hi) atomicAdd(&deg[d], 1);
        }
    }
}

__global__ void k_scan1(const int* __restrict__ deg, int* __restrict__ offs,
                        int* __restrict__ bsum) {
    __shared__ int s[1024];
    int t = threadIdx.x;
    int i = blockIdx.x * 1024 + t;
    int v = (i < NN) ? deg[i] : 0;
    s[t] = v;
    __syncthreads();
    for (int off = 1; off < 1024; off <<= 1) {
        int x = (t >= off) ? s[t - off] : 0;
        __syncthreads();
        s[t] += x;
        __syncthreads();
    }
    if (i < NN) offs[i] = s[t] - v;
    if (t == 1023) bsum[blockIdx.x] = s[t];
}

__global__ void k_scan2(int* __restrict__ bsum) {
    __shared__ int s[128];
    int t = threadIdx.x;
    int v = (t < 98) ? bsum[t] : 0;
    s[t] = v;
    __syncthreads();
    for (int off = 1; off < 128; off <<= 1) {
        int x = (t >= off) ? s[t - off] : 0;
        __syncthreads();
        s[t] += x;
        __syncthreads();
    }
    if (t < 98) bsum[t] = s[t] - v;
}

__global__ void k_scan3(int* __restrict__ offs, const int* __restrict__ bsum) {
    int i = blockIdx.x * 256 + threadIdx.x;
    if (i < NN) offs[i] += bsum[i >> 10];
}

__global__ __launch_bounds__(256) void k_fill(const int* __restrict__ src,
                                              const int* __restrict__ dst,
                                              const int* __restrict__ offs,
                                              int* __restrict__ fill,
                                              int* __restrict__ srcS) {
    int w = blockIdx.x & 7;
    int s = blockIdx.x >> 3;
    int lo = w * 12500, hi = lo + 12500;
    int e0 = s * 2048 + threadIdx.x;
#pragma unroll
    for (int i = 0; i < 8; i++) {
        int e = e0 + i * 256;
        if (e < NE) {
            int d = dst[e];
            if (d >= lo && d < hi) {
                int slot = offs[d] + atomicAdd(&fill[d], 1);
                srcS[slot] = src[e];
            }
        }
    }
}

// ------- u1 = z1 + gather-sum; bf16 rows (256 B), wave/node, unroll 4 --------
__global__ __launch_bounds__(256) void k_agg1(const ushort* __restrict__ z1bf,
                                              const int* __restrict__ offs,
                                              const int* __restrict__ deg,
                                              const int* __restrict__ srcS,
                                              float* __restrict__ u1) {
    int wq = __builtin_amdgcn_readfirstlane(threadIdx.x >> 6);
    int l = threadIdx.x & 63;
    int n = blockIdx.x * 4 + wq;
    if (n >= NN) return;
    int d = deg[n], base = offs[n];
    bool act = l < 50;
    const ushort* zc = z1bf + 2 * l;
    float a0 = 0.f, a1 = 0.f, b0 = 0.f, b1 = 0.f;
    float c0 = 0.f, c1 = 0.f, e0 = 0.f, e1 = 0.f;
    int i = 0;
    for (; i + 4 <= d; i += 4) {
        int s0 = srcS[base + i],     s1 = srcS[base + i + 1];
        int s2 = srcS[base + i + 2], s3 = srcS[base + i + 3];
        if (act) {
            uint x0 = *(const uint*)(zc + (size_t)s0 * 128);
            uint x1 = *(const uint*)(zc + (size_t)s1 * 128);
            uint x2 = *(const uint*)(zc + (size_t)s2 * 128);
            uint x3 = *(const uint*)(zc + (size_t)s3 * 128);
            a0 += bflo(x0); a1 += bfhi(x0);
            b0 += bflo(x1); b1 += bfhi(x1);
            c0 += bflo(x2); c1 += bfhi(x2);
            e0 += bflo(x3); e1 += bfhi(x3);
        }
    }
    for (; i < d; i++) {
        int s0 = srcS[base + i];
        if (act) {
            uint x0 = *(const uint*)(zc + (size_t)s0 * 128);
            a0 += bflo(x0); a1 += bfhi(x0);
        }
    }
    if (act) {
        uint xs = *(const uint*)(zc + (size_t)n * 128);
        float r0 = (a0 + b0) + (c0 + e0) + bflo(xs);
        float r1 = (a1 + b1) + (c1 + e1) + bfhi(xs);
        *(float2*)(u1 + (size_t)n * D1 + 2 * l) = make_float2(r0, r1);
    }
}

// ----- BN stats, two-stage (no atomics): blocks write partials, 1 block folds
__global__ __launch_bounds__(256) void k_bnstat100(const float* __restrict__ u,
                                                   float* __restrict__ pb) {
    __shared__ float ls[10][100], lq[10][100];
    int t = threadIdx.x;
    int r0 = blockIdx.x * 200;           // 500 blocks x 200 rows = 100000
    int r1 = r0 + 200; if (r1 > NN) r1 = NN;
    if (t < 250) {
        int sub = t / 25, q = t % 25;
        float4 S = make_float4(0, 0, 0, 0), Q = make_float4(0, 0, 0, 0);
        for (int r = r0 + sub; r < r1; r += 10) {
            float4 v = *(const float4*)(u + (size_t)r * 100 + 4 * q);
            S.x += v.x; S.y += v.y; S.z += v.z; S.w += v.w;
            Q.x = fmaf(v.x, v.x, Q.x); Q.y = fmaf(v.y, v.y, Q.y);
            Q.z = fmaf(v.z, v.z, Q.z); Q.w = fmaf(v.w, v.w, Q.w);
        }
        ls[sub][4 * q + 0] = S.x; ls[sub][4 * q + 1] = S.y;
        ls[sub][4 * q + 2] = S.z; ls[sub][4 * q + 3] = S.w;
        lq[sub][4 * q + 0] = Q.x; lq[sub][4 * q + 1] = Q.y;
        lq[sub][4 * q + 2] = Q.z; lq[sub][4 * q + 3] = Q.w;
    }
    __syncthreads();
    if (t < 100) {
        float S = 0.f, Q = 0.f;
#pragma unroll
        for (int s = 0; s < 10; s++) { S += ls[s][t]; Q += lq[s][t]; }
        pb[blockIdx.x * 200 + t] = S;
        pb[blockIdx.x * 200 + 100 + t] = Q;
    }
}

__global__ __launch_bounds__(512) void k_bnfin100(const float* __restrict__ pb,
                                                  const float* __restrict__ gamma,
                                                  const float* __restrict__ beta,
                                                  float* __restrict__ sc,
                                                  float* __restrict__ sh) {
    __shared__ float ls[4][100], lq[4][100];
    int t = threadIdx.x;
    if (t < 400) {
        int sub = t / 100, c = t % 100;
        float S = 0.f, Q = 0.f;
        for (int b = sub; b < 500; b += 4) {
            S += pb[b * 200 + c];
            Q += pb[b * 200 + 100 + c];
        }
        ls[sub][c] = S; lq[sub][c] = Q;
    }
    __syncthreads();
    if (t < 100) {
        float S = ls[0][t] + ls[1][t] + ls[2][t] + ls[3][t];
        float Q = lq[0][t] + lq[1][t] + lq[2][t] + lq[3][t];
        float mean = S * (1.f / NN);
        float var = Q * (1.f / NN) - mean * mean;
        float inv = rsqrtf(var + BN_EPS);
        float s = gamma[t] * inv;
        sc[t] = s;
        sh[t] = beta[t] - mean * s;
    }
}

__global__ __launch_bounds__(256) void k_bnstat20(const float* __restrict__ u,
                                                  float* __restrict__ pb) {
    __shared__ float ls[50][20], lq[50][20];
    int t = threadIdx.x;
    int r0 = blockIdx.x * 400;           // 250 blocks x 400 rows = 100000
    int r1 = r0 + 400; if (r1 > NN) r1 = NN;
    if (t < 250) {
        int sub = t / 5, q = t % 5;
        float4 S = make_float4(0, 0, 0, 0), Q = make_float4(0, 0, 0, 0);
        for (int r = r0 + sub; r < r1; r += 50) {
            float4 v = *(const float4*)(u + (size_t)r * 20 + 4 * q);
            S.x += v.x; S.y += v.y; S.z += v.z; S.w += v.w;
            Q.x = fmaf(v.x, v.x, Q.x); Q.y = fmaf(v.y, v.y, Q.y);
            Q.z = fmaf(v.z, v.z, Q.z); Q.w = fmaf(v.w, v.w, Q.w);
        }
        ls[sub][4 * q + 0] = S.x; ls[sub][4 * q + 1] = S.y;
        ls[sub][4 * q + 2] = S.z; ls[sub][4 * q + 3] = S.w;
        lq[sub][4 * q + 0] = Q.x; lq[sub][4 * q + 1] = Q.y;
        lq[sub][4 * q + 2] = Q.z; lq[sub][4 * q + 3] = Q.w;
    }
    __syncthreads();
    if (t < 20) {
        float S = 0.f, Q = 0.f;
#pragma unroll
        for (int s = 0; s < 50; s++) { S += ls[s][t]; Q += lq[s][t]; }
        pb[blockIdx.x * 40 + t] = S;
        pb[blockIdx.x * 40 + 20 + t] = Q;
    }
}

__global__ __launch_bounds__(512) void k_bnfin20(const float* __restrict__ pb,
                                                 const float* __restrict__ gamma,
                                                 const float* __restrict__ beta,
                                                 float* __restrict__ sc,
                                                 float* __restrict__ sh) {
    __shared__ float ls[25][20], lq[25][20];
    int t = threadIdx.x;
    if (t < 500) {
        int sub = t / 20, c = t % 20;
        float S = 0.f, Q = 0.f;
        for (int b = sub; b < 250; b += 25) {
            S += pb[b * 40 + c];
            Q += pb[b * 40 + 20 + c];
        }
        ls[sub][c] = S; lq[sub][c] = Q;
    }
    __syncthreads();
    if (t < 20) {
        float S = 0.f, Q = 0.f;
#pragma unroll
        for (int s = 0; s < 25; s++) { S += ls[s][t]; Q += lq[s][t]; }
        float mean = S * (1.f / NN);
        float var = Q * (1.f / NN) - mean * mean;
        float inv = rsqrtf(var + BN_EPS);
        float s = gamma[t] * inv;
        sc[t] = s;
        sh[t] = beta[t] - mean * s;
    }
}

// ------ fused: relu(bn1(u1)) @ g1_W2 + b2 -> relu -> @ g2_W1 = z2bf ----------
__global__ __launch_bounds__(256) void k_m2(const float* __restrict__ u1,
                                            const float* __restrict__ sc,
                                            const float* __restrict__ sh,
                                            const float* __restrict__ W2,   // [100][100]
                                            const float* __restrict__ b2,
                                            const float* __restrict__ W1p,  // [100][20]
                                            ushort* __restrict__ z2bf) {
    __shared__ float Xs[100 * 65];  // 26 KB
    int t = threadIdx.x;
    int row0 = blockIdx.x * 64;
#pragma unroll
    for (int i = 0; i < 25; i++) {
        int p = i * 256 + t;
        int r = p / 100, c = p % 100;
        int row = row0 + r; if (row >= NN) row = NN - 1;
        float v = u1[(size_t)row * D1 + c];
        v = fmaxf(v * sc[c] + sh[c], 0.f);
        Xs[c * 65 + r] = v;
    }
    __syncthreads();
    int cg = __builtin_amdgcn_readfirstlane(t >> 6);
    int r = t & 63;
    int j0 = cg * 25;
    float H[25];
#pragma unroll
    for (int m = 0; m < 25; m++) H[m] = 0.f;
    for (int k = 0; k < D1; k++) {
        float a = Xs[k * 65 + r];
        const float* wr = W2 + k * D1 + j0;  // wave-uniform -> s_load
#pragma unroll
        for (int m = 0; m < 25; m++) H[m] = fmaf(a, wr[m], H[m]);
    }
#pragma unroll
    for (int m = 0; m < 25; m++) H[m] = fmaxf(H[m] + b2[j0 + m], 0.f);
    float pz[20];
#pragma unroll
    for (int c = 0; c < 20; c++) pz[c] = 0.f;
#pragma unroll
    for (int m = 0; m < 25; m++) {
        const float* wp = W1p + (j0 + m) * D2;  // wave-uniform -> s_load
#pragma unroll
        for (int c = 0; c < 20; c++) pz[c] = fmaf(H[m], wp[c], pz[c]);
    }
    __syncthreads();
    float* red = Xs;  // 256x20 = 20.5 KB
#pragma unroll
    for (int c = 0; c < 20; c++) red[t * 20 + c] = pz[c];
    __syncthreads();
#pragma unroll
    for (int i = 0; i < 3; i++) {
        int p = i * 256 + t;          // 640 ushort2 = 64 rows x 10 pairs
        if (p < 640) {
            int rr = p / 10, c2 = 2 * (p % 10);
            int row = row0 + rr;
            if (row < NN) {
                float v0 = red[rr * 20 + c2] + red[(64 + rr) * 20 + c2] +
                           red[(128 + rr) * 20 + c2] + red[(192 + rr) * 20 + c2];
                float v1 = red[rr * 20 + c2 + 1] + red[(64 + rr) * 20 + c2 + 1] +
                           red[(128 + rr) * 20 + c2 + 1] + red[(192 + rr) * 20 + c2 + 1];
                *(uint*)(z2bf + (size_t)row * 32 + c2) = packbf2(v0, v1);
            }
        }
    }
}

// ------- u2 = z2 + gather-sum; bf16 rows padded to 32 (64 B, 1 line) ---------
__global__ __launch_bounds__(256) void k_agg2(const ushort* __restrict__ z2bf,
                                              const int* __restrict__ offs,
                                              const int* __restrict__ deg,
                                              const int* __restrict__ srcS,
                                              float* __restrict__ u2) {
    int t = threadIdx.x;
    if (t >= 250) return;
    int n = blockIdx.x * 25 + t / 10;
    if (n >= NN) return;
    int c2 = 2 * (t % 10);
    int d = deg[n], base = offs[n];
    const ushort* zc = z2bf + c2;
    float a0 = 0.f, a1 = 0.f, b0 = 0.f, b1 = 0.f;
    int i = 0;
    for (; i + 2 <= d; i += 2) {
        uint x0 = *(const uint*)(zc + (size_t)srcS[base + i] * 32);
        uint x1 = *(const uint*)(zc + (size_t)srcS[base + i + 1] * 32);
        a0 += bflo(x0); a1 += bfhi(x0);
        b0 += bflo(x1); b1 += bfhi(x1);
    }
    if (i < d) {
        uint x0 = *(const uint*)(zc + (size_t)srcS[base + i] * 32);
        a0 += bflo(x0); a1 += bfhi(x0);
    }
    uint xs = *(const uint*)(zc + (size_t)n * 32);
    *(float2*)(u2 + (size_t)n * D2 + c2) =
        make_float2(a0 + b0 + bflo(xs), a1 + b1 + bfhi(xs));
}

// ------ fused: relu(bn2(u2)) @ g2_W2 + b2 -> relu = h2 ------------
__global__ __launch_bounds__(256) void k_m3(const float* __restrict__ u2,
                                            const float* __restrict__ sc,
                                            const float* __restrict__ sh,
                                            const float* __restrict__ W2pT,
                                            const float* __restrict__ b2p,
                                            float* __restrict__ h2) {
    int row = blockIdx.x * 256 + threadIdx.x;
    if (row >= NN) return;
    float4 y[5];
    const float4* up = (const float4*)(u2 + (size_t)row * D2);
#pragma unroll
    for (int i = 0; i < 5; i++) {
        float4 v = up[i];
        float4 S = *(const float4*)(sc + 4 * i);
        float4 H = *(const float4*)(sh + 4 * i);
        v.x = fmaxf(v.x * S.x + H.x, 0.f);
        v.y = fmaxf(v.y * S.y + H.y, 0.f);
        v.z = fmaxf(v.z * S.z + H.z, 0.f);
        v.w = fmaxf(v.w * S.w + H.w, 0.f);
        y[i] = v;
    }
    float hrow[D2];
#pragma unroll
    for (int j = 0; j < D2; j++) {
        float h = b2p[j];
        const float4* w = (const float4*)(W2pT + j * D2);
#pragma unroll
        for (int kk = 0; kk < 5; kk++) {
            float4 a = y[kk], b = w[kk];
            h += a.x * b.x + a.y * b.y + a.z * b.z + a.w * b.w;
        }
        hrow[j] = fmaxf(h, 0.f);
    }
    float* hr = h2 + (size_t)row * D2;
#pragma unroll
    for (int c = 0; c < D2; c += 4) {
        float4 o; o.x = hrow[c]; o.y = hrow[c + 1]; o.z = hrow[c + 2]; o.w = hrow[c + 3];
        *(float4*)(hr + c) = o;
    }
}

// ---------------- per-graph ranges (node2graph is sorted) ----------------
__global__ void k_starts(const int* __restrict__ n2g, int* __restrict__ starts) {
    int i = blockIdx.x * 256 + threadIdx.x;
    if (i >= NN) return;
    int g = n2g[i];
    if (i == 0) {
        for (int x = 0; x <= g; x++) starts[x] = 0;
    } else {
        int gp = n2g[i - 1];
        for (int x = gp + 1; x <= g; x++) starts[x] = i;
    }
    if (i == NN - 1) {
        for (int x = g + 1; x <= NG; x++) starts[x] = NN;
    }
}

// ---- wave per graph: 60 lanes = 3 row-stripes x 20 cols, shuffle-reduce -----
__global__ __launch_bounds__(256) void k_pool(const float* __restrict__ h2,
                                              const int* __restrict__ starts,
                                              float* __restrict__ hg) {
    int wq = __builtin_amdgcn_readfirstlane(threadIdx.x >> 6);
    int l = threadIdx.x & 63;
    int g = blockIdx.x * 4 + wq;
    if (g >= NG) return;
    int s0 = starts[g], s1 = starts[g + 1];
    float a = 0.f;
    if (l < 60) {
        int rg = l / 20, c = l % 20;
        for (int n = s0 + rg; n < s1; n += 3) a += h2[(size_t)n * D2 + c];
    }
    float v1 = __shfl(a, l + 20, 64);
    float v2 = __shfl(a, l + 40, 64);
    if (l < 20) {
        float cnt = (float)(s1 - s0);
        hg[g * D2 + l] = (a + v1 + v2) / fmaxf(cnt, 1.f);
    }
}

// ---------------- a1 = kron(hg, self_feat) @ fc1_W ----------------
__global__ void k_head1(const float* __restrict__ hg, const float* __restrict__ sf,
                        const float* __restrict__ fc1W, float* __restrict__ a1) {
    int b = blockIdx.x * 8 + threadIdx.x / 32;
    int c = threadIdx.x % 32;
    if (b >= NG) return;
    const float* hgb = hg + b * D2;
    const float* sfb = sf + b * DSELF;
    float acc = 0.f;
    for (int i = 0; i < D2; i++) {
        float hi = hgb[i];
#pragma unroll
        for (int j = 0; j < DSELF; j++)
            acc += hi * sfb[j] * fc1W[(i * DSELF + j) * 32 + c];
    }
    a1[b * 32 + c] = acc;
}

// ---------------- single-block head: bn1->relu->fc2->bn2->relu->fc3 ----------
__global__ __launch_bounds__(1024) void k_head2(
    const float* __restrict__ a1, const float* __restrict__ g1,
    const float* __restrict__ be1, const float* __restrict__ fc2W,
    const float* __restrict__ g2, const float* __restrict__ be2,
    const float* __restrict__ fc3W, const float* __restrict__ fc3b,
    float* __restrict__ out) {
    int t = threadIdx.x;
    int lane = t & 63, w = t >> 6;
    __shared__ float s1[16][32], s2[16][32];
    __shared__ float sc[32], sh[32], sc2[8], sh2[8];
    float x[32];
    const float4* ap = (const float4*)(a1 + t * 32);
#pragma unroll
    for (int i = 0; i < 8; i++) {
        float4 v = ap[i];
        x[4 * i] = v.x; x[4 * i + 1] = v.y; x[4 * i + 2] = v.z; x[4 * i + 3] = v.w;
    }
#pragma unroll
    for (int c = 0; c < 32; c++) {
        float v = x[c], q = v * v;
        for (int o = 32; o > 0; o >>= 1) {
            v += __shfl_down(v, o, 64);
            q += __shfl_down(q, o, 64);
        }
        if (lane == 0) { s1[w][c] = v; s2[w][c] = q; }
    }
    __syncthreads();
    if (t < 32) {
        float s = 0.f, q = 0.f;
        for (int ww = 0; ww < 16; ww++) { s += s1[ww][t]; q += s2[ww][t]; }
        float mean = s * (1.f / NG);
        float var = q * (1.f / NG) - mean * mean;
        float inv = rsqrtf(var + BN_EPS);
        float scl = g1[t] * inv;
        sc[t] = scl;
        sh[t] = be1[t] - mean * scl;
    }
    __syncthreads();
#pragma unroll
    for (int c = 0; c < 32; c++) x[c] = fmaxf(x[c] * sc[c] + sh[c], 0.f);
    float y[8];
#pragma unroll
    for (int p = 0; p < 8; p++) {
        float a = 0.f;
#pragma unroll
        for (int c = 0; c < 32; c++) a += x[c] * fc2W[c * 8 + p];
        y[p] = a;
    }
    __syncthreads();
#pragma unroll
    for (int p = 0; p < 8; p++) {
        float v = y[p], q = v * v;
        for (int o = 32; o > 0; o >>= 1) {
            v += __shfl_down(v, o, 64);
            q += __shfl_down(q, o, 64);
        }
        if (lane == 0) { s1[w][p] = v; s2[w][p] = q; }
    }
    __syncthreads();
    if (t < 8) {
        float s = 0.f, q = 0.f;
        for (int ww = 0; ww < 16; ww++) { s += s1[ww][t]; q += s2[ww][t]; }
        float mean = s * (1.f / NG);
        float var = q * (1.f / NG) - mean * mean;
        float inv = rsqrtf(var + BN_EPS);
        float scl = g2[t] * inv;
        sc2[t] = scl;
        sh2[t] = be2[t] - mean * scl;
    }
    __syncthreads();
    float o = fc3b[0];
#pragma unroll
    for (int p = 0; p < 8; p++) {
        float yy = fmaxf(y[p] * sc2[p] + sh2[p], 0.f);
        o += yy * fc3W[p];
    }
    out[t] = o;
}

extern "C" void kernel_launch(void* const* d_in, const int* in_sizes, int n_in,
                              void* d_out, int out_size, void* d_ws, size_t ws_size,
                              hipStream_t stream) {
    const float* feat    = (const float*)d_in[0];
    const float* sf      = (const float*)d_in[1];
    const int*   esrc    = (const int*)d_in[2];
    const int*   edst    = (const int*)d_in[3];
    const int*   n2g     = (const int*)d_in[4];
    const float* g1W1    = (const float*)d_in[5];
    const float* g1gam   = (const float*)d_in[7];
    const float* g1bet   = (const float*)d_in[8];
    const float* g1W2    = (const float*)d_in[9];
    const float* g1b2    = (const float*)d_in[10];
    const float* g2W1    = (const float*)d_in[11];
    const float* g2gam   = (const float*)d_in[13];
    const float* g2bet   = (const float*)d_in[14];
    const float* g2W2    = (const float*)d_in[15];
    const float* g2b2    = (const float*)d_in[16];
    const float* fc1W    = (const float*)d_in[17];
    const float* hbn1g   = (const float*)d_in[19];
    const float* hbn1b   = (const float*)d_in[20];
    const float* fc2W    = (const float*)d_in[21];
    const float* hbn2g   = (const float*)d_in[23];
    const float* hbn2b   = (const float*)d_in[24];
    const float* fc3W    = (const float*)d_in[25];
    const float* fc3b    = (const float*)d_in[26];
    float* out = (float*)d_out;

    char* w = (char*)d_ws;
    size_t off = 0;
    auto alloc = [&](size_t bytes) -> char* {
        char* p = w + off;
        off += (bytes + 15) & ~(size_t)15;
        return p;
    };
    // region A: z1bf [100k x 128 bf16] = 25.6 MB; after k_agg1 z1bf is dead and
    // the region is re-used as z2bf (6.4 MB) + u2 (8 MB) + h2 (8 MB) = 22.4 MB
    char* regA = alloc((size_t)NN * 128 * 2);
    ushort* z1bf = (ushort*)regA;
    ushort* z2bf = (ushort*)regA;
    float*  u2   = (float*)(regA + 6400000);
    float*  h2   = (float*)(regA + 14400000);
    float* u1 = (float*)alloc((size_t)NN * D1 * 4);  // 40 MB
    char* zero_base = w + off;
    int*   deg   = (int*)alloc(NN * 4);
    int*   fill  = (int*)alloc(NN * 4);
    size_t zero_sz = (size_t)((w + off) - zero_base);
    int*   offs  = (int*)alloc(NN * 4);
    int*   bsum  = (int*)alloc(128 * 4);
    int*   srcS  = (int*)alloc((size_t)NE * 4);
    int*   starts= (int*)alloc((NG + 1) * 4);
    float* W2pT  = (float*)alloc(D2 * D2 * 4);
    float* pb1   = (float*)alloc(500 * 200 * 4);   // bnstat100 partials
    float* pb2   = (float*)alloc(250 * 40 * 4);    // bnstat20 partials
    float* sc1   = (float*)alloc(D1 * 4);
    float* sh1   = (float*)alloc(D1 * 4);
    float* sc2   = (float*)alloc(D2 * 4);
    float* sh2   = (float*)alloc(D2 * 4);
    float* hg    = (float*)alloc(NG * D2 * 4);
    float* a1    = (float*)alloc(NG * 32 * 4);
    (void)in_sizes; (void)n_in; (void)out_size; (void)ws_size;

    hipMemsetAsync(zero_base, 0, zero_sz, stream);

    k_prep<<<2, 256, 0, stream>>>(g2W2, W2pT);
    k_gemm1<<<(NN + 63) / 64, 256, 0, stream>>>(feat, g1W1, z1bf);

    // 782 slices x 8 XCD-affine windows; each block covers 2048 edges
    k_deg<<<782 * 8, 256, 0, stream>>>(edst, deg);
    k_scan1<<<98, 1024, 0, stream>>>(deg, offs, bsum);
    k_scan2<<<1, 128, 0, stream>>>(bsum);
    k_scan3<<<(NN + 255) / 256, 256, 0, stream>>>(offs, bsum);
    k_fill<<<782 * 8, 256, 0, stream>>>(esrc, edst, offs, fill, srcS);

    k_agg1<<<(NN + 3) / 4, 256, 0, stream>>>(z1bf, offs, deg, srcS, u1);
    k_bnstat100<<<500, 256, 0, stream>>>(u1, pb1);
    k_bnfin100<<<1, 512, 0, stream>>>(pb1, g1gam, g1bet, sc1, sh1);
    k_m2<<<(NN + 63) / 64, 256, 0, stream>>>(u1, sc1, sh1, g1W2, g1b2, g2W1, z2bf);

    k_agg2<<<(NN + 24) / 25, 256, 0, stream>>>(z2bf, offs, deg, srcS, u2);
    k_bnstat20<<<250, 256, 0, stream>>>(u2, pb2);
    k_bnfin20<<<1, 512, 0, stream>>>(pb2, g2gam, g2bet, sc2, sh2);
    k_m3<<<(NN + 255) / 256, 256, 0, stream>>>(u2, sc2, sh2, W2pT, g2b2, h2);

    k_starts<<<(NN + 255) / 256, 256, 0, stream>>>(n2g, starts);
    k_pool<<<(NG + 3) / 4, 256, 0, stream>>>(h2, starts, hg);
    k_head1<<<NG / 8, 256, 0, stream>>>(hg, sf, fc1W, a1);
    k_head2<<<1, 1024, 0, stream>>>(a1, hbn1g, hbn1b, fc2W, hbn2g, hbn2b, fc3W, fc3b, out);
}

// Round 7
// 486.539 us; speedup vs baseline: 1.6770x; 1.2075x over previous
//
#include <hip/hip_runtime.h>

#define NN 100000
#define NE 1600000
#define NG 1024
#define DIN 128
#define D1 100
#define D2 20
#define DSELF 16
#define BN_EPS 1e-5f

#define NB 391      // node buckets of 256 nodes
#define NBLK 782    // edge slice blocks (2048 edges each)
#define EPB 2048
#define RAWCAP 5120 // max edges per bucket (mean 4096, +16 sigma)

typedef unsigned int uint;
typedef unsigned short ushort;

__device__ inline float bflo(uint x) { return __uint_as_float(x << 16); }
__device__ inline float bfhi(uint x) { return __uint_as_float(x & 0xffff0000u); }
__device__ inline uint packbf2(float a, float b) {  // round-nearest-even bf16 pair
    uint ua = __float_as_uint(a), ub = __float_as_uint(b);
    ua += 0x7fffu + ((ua >> 16) & 1u);
    ub += 0x7fffu + ((ub >> 16) & 1u);
    return (ua >> 16) | (ub & 0xffff0000u);
}

// ------- z1bf = bf16(feat @ W1), rows padded to 128 cols (256 B aligned) -----
__global__ __launch_bounds__(256) void k_gemm1(const float* __restrict__ feat,
                                               const float* __restrict__ W1,
                                               ushort* __restrict__ z1bf) {
    __shared__ float As[128 * 65];
    int t = threadIdx.x;
    int row0 = blockIdx.x * 64;
#pragma unroll
    for (int i = 0; i < 8; i++) {
        int p = i * 256 + t;
        int r = p >> 5, cq = p & 31;
        int row = row0 + r; if (row >= NN) row = NN - 1;
        float4 v = *(const float4*)(feat + (size_t)row * DIN + cq * 4);
        As[(4 * cq + 0) * 65 + r] = v.x;
        As[(4 * cq + 1) * 65 + r] = v.y;
        As[(4 * cq + 2) * 65 + r] = v.z;
        As[(4 * cq + 3) * 65 + r] = v.w;
    }
    __syncthreads();
    int cg = __builtin_amdgcn_readfirstlane(t >> 6);
    int r = t & 63;
    int j0 = cg * 25;
    float acc[25];
#pragma unroll
    for (int m = 0; m < 25; m++) acc[m] = 0.f;
    for (int k = 0; k < DIN; k++) {
        float a = As[k * 65 + r];
        const float* wr = W1 + k * D1 + j0;  // wave-uniform -> s_load
#pragma unroll
        for (int m = 0; m < 25; m++) acc[m] = fmaf(a, wr[m], acc[m]);
    }
    __syncthreads();
#pragma unroll
    for (int m = 0; m < 25; m++) As[r * 100 + j0 + m] = acc[m];
    __syncthreads();
#pragma unroll
    for (int i = 0; i < 13; i++) {
        int p = i * 256 + t;
        if (p < 3200) {
            int rr = p / 50, cc = 2 * (p % 50);
            int row = row0 + rr;
            if (row < NN) {
                float v0 = As[rr * 100 + cc], v1 = As[rr * 100 + cc + 1];
                *(uint*)(z1bf + (size_t)row * 128 + cc) = packbf2(v0, v1);
            }
        }
    }
}

// ======== deterministic CSR build: two-level counting sort, no global atomics
// A1: per-(bucket,block) histogram, dense writes
__global__ __launch_bounds__(256) void k_csrA1(const int* __restrict__ dst,
                                               int* __restrict__ pbcount) {
    __shared__ int h[NB];
    int t = threadIdx.x, blk = blockIdx.x;
    for (int i = t; i < NB; i += 256) h[i] = 0;
    __syncthreads();
    int e0 = blk * EPB + t;
#pragma unroll
    for (int i = 0; i < 8; i++) {
        int e = e0 + i * 256;
        if (e < NE) atomicAdd(&h[dst[e] >> 8], 1);
    }
    __syncthreads();
    for (int i = t; i < NB; i += 256) pbcount[i * NBLK + blk] = h[i];
}

// S1: per-bucket exclusive scan over 782 blocks (in-place) + bucket totals
__global__ __launch_bounds__(1024) void k_csrS1(int* __restrict__ pbcount,
                                                int* __restrict__ btot) {
    __shared__ int s[1024];
    int t = threadIdx.x, b = blockIdx.x;
    int v = (t < NBLK) ? pbcount[b * NBLK + t] : 0;
    s[t] = v;
    __syncthreads();
    for (int off = 1; off < 1024; off <<= 1) {
        int x = (t >= off) ? s[t - off] : 0;
        __syncthreads();
        s[t] += x;
        __syncthreads();
    }
    if (t < NBLK) pbcount[b * NBLK + t] = s[t] - v;
    if (t == 1023) btot[b] = s[t];
}

// S2: exclusive scan over 391 bucket totals -> ebase[0..NB], ebase[NB] = NE
__global__ __launch_bounds__(512) void k_csrS2(const int* __restrict__ btot,
                                               int* __restrict__ ebase) {
    __shared__ int s[512];
    int t = threadIdx.x;
    int v = (t < NB) ? btot[t] : 0;
    s[t] = v;
    __syncthreads();
    for (int off = 1; off < 512; off <<= 1) {
        int x = (t >= off) ? s[t - off] : 0;
        __syncthreads();
        s[t] += x;
        __syncthreads();
    }
    if (t < NB) ebase[t] = s[t] - v;
    if (t == NB - 1) ebase[NB] = s[t];
}

// A2: append packed (src | local<<17) into exact per-(bucket,block) ranges
__global__ __launch_bounds__(256) void k_csrA2(const int* __restrict__ src,
                                               const int* __restrict__ dst,
                                               const int* __restrict__ pbexcl,
                                               const int* __restrict__ ebase,
                                               uint* __restrict__ gbuf) {
    __shared__ int cur[NB];
    int t = threadIdx.x, blk = blockIdx.x;
    for (int i = t; i < NB; i += 256) cur[i] = ebase[i] + pbexcl[i * NBLK + blk];
    __syncthreads();
    int e0 = blk * EPB + t;
#pragma unroll
    for (int i = 0; i < 8; i++) {
        int e = e0 + i * 256;
        if (e < NE) {
            int d = dst[e];
            int b = d >> 8;
            int pos = atomicAdd(&cur[b], 1);
            gbuf[pos] = (uint)src[e] | ((uint)(d & 255) << 17);
        }
    }
}

// B: per-bucket LDS counting sort by local dst -> deg, offs, srcS (all dense)
__global__ __launch_bounds__(256) void k_csrB(const uint* __restrict__ gbuf,
                                              const int* __restrict__ ebase,
                                              int* __restrict__ deg,
                                              int* __restrict__ offs,
                                              int* __restrict__ srcS) {
    __shared__ uint raw[RAWCAP];
    __shared__ int srt[RAWCAP];
    __shared__ int pref[256], cur[256];
    int t = threadIdx.x, b = blockIdx.x;
    int e0 = ebase[b], e1 = ebase[b + 1];
    int cnt = e1 - e0; if (cnt > RAWCAP) cnt = RAWCAP;
    cur[t] = 0;
    for (int i = t; i < cnt; i += 256) raw[i] = gbuf[e0 + i];
    __syncthreads();
    for (int i = t; i < cnt; i += 256) atomicAdd(&cur[raw[i] >> 17], 1);
    __syncthreads();
    int v = cur[t];
    pref[t] = v;
    __syncthreads();
    for (int off = 1; off < 256; off <<= 1) {
        int x = (t >= off) ? pref[t - off] : 0;
        __syncthreads();
        pref[t] += x;
        __syncthreads();
    }
    int excl = pref[t] - v;
    int node = b * 256 + t;
    if (node < NN) { deg[node] = v; offs[node] = e0 + excl; }
    cur[t] = excl;
    __syncthreads();
    for (int i = t; i < cnt; i += 256) {
        uint p = raw[i];
        int lpos = atomicAdd(&cur[p >> 17], 1);
        srt[lpos] = (int)(p & 0x1FFFFu);
    }
    __syncthreads();
    for (int i = t; i < cnt; i += 256) srcS[e0 + i] = srt[i];
}

// ------- u1 = z1 + gather-sum; bf16 rows (256 B), wave/node, unroll 4 --------
__global__ __launch_bounds__(256) void k_agg1(const ushort* __restrict__ z1bf,
                                              const int* __restrict__ offs,
                                              const int* __restrict__ deg,
                                              const int* __restrict__ srcS,
                                              float* __restrict__ u1) {
    int wq = __builtin_amdgcn_readfirstlane(threadIdx.x >> 6);
    int l = threadIdx.x & 63;
    int n = blockIdx.x * 4 + wq;
    if (n >= NN) return;
    int d = deg[n], base = offs[n];
    bool act = l < 50;
    const ushort* zc = z1bf + 2 * l;
    float a0 = 0.f, a1 = 0.f, b0 = 0.f, b1 = 0.f;
    float c0 = 0.f, c1 = 0.f, e0 = 0.f, e1 = 0.f;
    int i = 0;
    for (; i + 4 <= d; i += 4) {
        int s0 = srcS[base + i],     s1 = srcS[base + i + 1];
        int s2 = srcS[base + i + 2], s3 = srcS[base + i + 3];
        if (act) {
            uint x0 = *(const uint*)(zc + (size_t)s0 * 128);
            uint x1 = *(const uint*)(zc + (size_t)s1 * 128);
            uint x2 = *(const uint*)(zc + (size_t)s2 * 128);
            uint x3 = *(const uint*)(zc + (size_t)s3 * 128);
            a0 += bflo(x0); a1 += bfhi(x0);
            b0 += bflo(x1); b1 += bfhi(x1);
            c0 += bflo(x2); c1 += bfhi(x2);
            e0 += bflo(x3); e1 += bfhi(x3);
        }
    }
    for (; i < d; i++) {
        int s0 = srcS[base + i];
        if (act) {
            uint x0 = *(const uint*)(zc + (size_t)s0 * 128);
            a0 += bflo(x0); a1 += bfhi(x0);
        }
    }
    if (act) {
        uint xs = *(const uint*)(zc + (size_t)n * 128);
        float r0 = (a0 + b0) + (c0 + e0) + bflo(xs);
        float r1 = (a1 + b1) + (c1 + e1) + bfhi(xs);
        *(float2*)(u1 + (size_t)n * D1 + 2 * l) = make_float2(r0, r1);
    }
}

// ----- BN stats, two-stage (no atomics): blocks write partials, 1 block folds
__global__ __launch_bounds__(256) void k_bnstat100(const float* __restrict__ u,
                                                   float* __restrict__ pb) {
    __shared__ float ls[10][100], lq[10][100];
    int t = threadIdx.x;
    int r0 = blockIdx.x * 200;
    int r1 = r0 + 200; if (r1 > NN) r1 = NN;
    if (t < 250) {
        int sub = t / 25, q = t % 25;
        float4 S = make_float4(0, 0, 0, 0), Q = make_float4(0, 0, 0, 0);
        for (int r = r0 + sub; r < r1; r += 10) {
            float4 v = *(const float4*)(u + (size_t)r * 100 + 4 * q);
            S.x += v.x; S.y += v.y; S.z += v.z; S.w += v.w;
            Q.x = fmaf(v.x, v.x, Q.x); Q.y = fmaf(v.y, v.y, Q.y);
            Q.z = fmaf(v.z, v.z, Q.z); Q.w = fmaf(v.w, v.w, Q.w);
        }
        ls[sub][4 * q + 0] = S.x; ls[sub][4 * q + 1] = S.y;
        ls[sub][4 * q + 2] = S.z; ls[sub][4 * q + 3] = S.w;
        lq[sub][4 * q + 0] = Q.x; lq[sub][4 * q + 1] = Q.y;
        lq[sub][4 * q + 2] = Q.z; lq[sub][4 * q + 3] = Q.w;
    }
    __syncthreads();
    if (t < 100) {
        float S = 0.f, Q = 0.f;
#pragma unroll
        for (int s = 0; s < 10; s++) { S += ls[s][t]; Q += lq[s][t]; }
        pb[blockIdx.x * 200 + t] = S;
        pb[blockIdx.x * 200 + 100 + t] = Q;
    }
}

__global__ __launch_bounds__(512) void k_bnfin100(const float* __restrict__ pb,
                                                  const float* __restrict__ gamma,
                                                  const float* __restrict__ beta,
                                                  float* __restrict__ sc,
                                                  float* __restrict__ sh) {
    __shared__ float ls[4][100], lq[4][100];
    int t = threadIdx.x;
    if (t < 400) {
        int sub = t / 100, c = t % 100;
        float S = 0.f, Q = 0.f;
        for (int b = sub; b < 500; b += 4) {
            S += pb[b * 200 + c];
            Q += pb[b * 200 + 100 + c];
        }
        ls[sub][c] = S; lq[sub][c] = Q;
    }
    __syncthreads();
    if (t < 100) {
        float S = ls[0][t] + ls[1][t] + ls[2][t] + ls[3][t];
        float Q = lq[0][t] + lq[1][t] + lq[2][t] + lq[3][t];
        float mean = S * (1.f / NN);
        float var = Q * (1.f / NN) - mean * mean;
        float inv = rsqrtf(var + BN_EPS);
        float s = gamma[t] * inv;
        sc[t] = s;
        sh[t] = beta[t] - mean * s;
    }
}

__global__ __launch_bounds__(256) void k_bnstat20(const float* __restrict__ u,
                                                  float* __restrict__ pb) {
    __shared__ float ls[50][20], lq[50][20];
    int t = threadIdx.x;
    int r0 = blockIdx.x * 400;
    int r1 = r0 + 400; if (r1 > NN) r1 = NN;
    if (t < 250) {
        int sub = t / 5, q = t % 5;
        float4 S = make_float4(0, 0, 0, 0), Q = make_float4(0, 0, 0, 0);
        for (int r = r0 + sub; r < r1; r += 50) {
            float4 v = *(const float4*)(u + (size_t)r * 20 + 4 * q);
            S.x += v.x; S.y += v.y; S.z += v.z; S.w += v.w;
            Q.x = fmaf(v.x, v.x, Q.x); Q.y = fmaf(v.y, v.y, Q.y);
            Q.z = fmaf(v.z, v.z, Q.z); Q.w = fmaf(v.w, v.w, Q.w);
        }
        ls[sub][4 * q + 0] = S.x; ls[sub][4 * q + 1] = S.y;
        ls[sub][4 * q + 2] = S.z; ls[sub][4 * q + 3] = S.w;
        lq[sub][4 * q + 0] = Q.x; lq[sub][4 * q + 1] = Q.y;
        lq[sub][4 * q + 2] = Q.z; lq[sub][4 * q + 3] = Q.w;
    }
    __syncthreads();
    if (t < 20) {
        float S = 0.f, Q = 0.f;
#pragma unroll
        for (int s = 0; s < 50; s++) { S += ls[s][t]; Q += lq[s][t]; }
        pb[blockIdx.x * 40 + t] = S;
        pb[blockIdx.x * 40 + 20 + t] = Q;
    }
}

__global__ __launch_bounds__(512) void k_bnfin20(const float* __restrict__ pb,
                                                 const float* __restrict__ gamma,
                                                 const float* __restrict__ beta,
                                                 float* __restrict__ sc,
                                                 float* __restrict__ sh) {
    __shared__ float ls[25][20], lq[25][20];
    int t = threadIdx.x;
    if (t < 500) {
        int sub = t / 20, c = t % 20;
        float S = 0.f, Q = 0.f;
        for (int b = sub; b < 250; b += 25) {
            S += pb[b * 40 + c];
            Q += pb[b * 40 + 20 + c];
        }
        ls[sub][c] = S; lq[sub][c] = Q;
    }
    __syncthreads();
    if (t < 20) {
        float S = 0.f, Q = 0.f;
#pragma unroll
        for (int s = 0; s < 25; s++) { S += ls[s][t]; Q += lq[s][t]; }
        float mean = S * (1.f / NN);
        float var = Q * (1.f / NN) - mean * mean;
        float inv = rsqrtf(var + BN_EPS);
        float s = gamma[t] * inv;
        sc[t] = s;
        sh[t] = beta[t] - mean * s;
    }
}

// ------ fused: relu(bn1(u1)) @ g1_W2 + b2 -> relu -> @ g2_W1 = z2bf ----------
__global__ __launch_bounds__(256) void k_m2(const float* __restrict__ u1,
                                            const float* __restrict__ sc,
                                            const float* __restrict__ sh,
                                            const float* __restrict__ W2,   // [100][100]
                                            const float* __restrict__ b2,
                                            const float* __restrict__ W1p,  // [100][20]
                                            ushort* __restrict__ z2bf) {
    __shared__ float Xs[100 * 65];
    int t = threadIdx.x;
    int row0 = blockIdx.x * 64;
#pragma unroll
    for (int i = 0; i < 25; i++) {
        int p = i * 256 + t;
        int r = p / 100, c = p % 100;
        int row = row0 + r; if (row >= NN) row = NN - 1;
        float v = u1[(size_t)row * D1 + c];
        v = fmaxf(v * sc[c] + sh[c], 0.f);
        Xs[c * 65 + r] = v;
    }
    __syncthreads();
    int cg = __builtin_amdgcn_readfirstlane(t >> 6);
    int r = t & 63;
    int j0 = cg * 25;
    float H[25];
#pragma unroll
    for (int m = 0; m < 25; m++) H[m] = 0.f;
    for (int k = 0; k < D1; k++) {
        float a = Xs[k * 65 + r];
        const float* wr = W2 + k * D1 + j0;  // wave-uniform -> s_load
#pragma unroll
        for (int m = 0; m < 25; m++) H[m] = fmaf(a, wr[m], H[m]);
    }
#pragma unroll
    for (int m = 0; m < 25; m++) H[m] = fmaxf(H[m] + b2[j0 + m], 0.f);
    float pz[20];
#pragma unroll
    for (int c = 0; c < 20; c++) pz[c] = 0.f;
#pragma unroll
    for (int m = 0; m < 25; m++) {
        const float* wp = W1p + (j0 + m) * D2;  // wave-uniform -> s_load
#pragma unroll
        for (int c = 0; c < 20; c++) pz[c] = fmaf(H[m], wp[c], pz[c]);
    }
    __syncthreads();
    float* red = Xs;
#pragma unroll
    for (int c = 0; c < 20; c++) red[t * 20 + c] = pz[c];
    __syncthreads();
#pragma unroll
    for (int i = 0; i < 3; i++) {
        int p = i * 256 + t;
        if (p < 640) {
            int rr = p / 10, c2 = 2 * (p % 10);
            int row = row0 + rr;
            if (row < NN) {
                float v0 = red[rr * 20 + c2] + red[(64 + rr) * 20 + c2] +
                           red[(128 + rr) * 20 + c2] + red[(192 + rr) * 20 + c2];
                float v1 = red[rr * 20 + c2 + 1] + red[(64 + rr) * 20 + c2 + 1] +
                           red[(128 + rr) * 20 + c2 + 1] + red[(192 + rr) * 20 + c2 + 1];
                *(uint*)(z2bf + (size_t)row * 32 + c2) = packbf2(v0, v1);
            }
        }
    }
}

// ------- u2 = z2 + gather-sum; bf16 rows padded to 32 (64 B, 1 line) ---------
__global__ __launch_bounds__(256) void k_agg2(const ushort* __restrict__ z2bf,
                                              const int* __restrict__ offs,
                                              const int* __restrict__ deg,
                                              const int* __restrict__ srcS,
                                              float* __restrict__ u2) {
    int t = threadIdx.x;
    if (t >= 250) return;
    int n = blockIdx.x * 25 + t / 10;
    if (n >= NN) return;
    int c2 = 2 * (t % 10);
    int d = deg[n], base = offs[n];
    const ushort* zc = z2bf + c2;
    float a0 = 0.f, a1 = 0.f, b0 = 0.f, b1 = 0.f;
    int i = 0;
    for (; i + 2 <= d; i += 2) {
        uint x0 = *(const uint*)(zc + (size_t)srcS[base + i] * 32);
        uint x1 = *(const uint*)(zc + (size_t)srcS[base + i + 1] * 32);
        a0 += bflo(x0); a1 += bfhi(x0);
        b0 += bflo(x1); b1 += bfhi(x1);
    }
    if (i < d) {
        uint x0 = *(const uint*)(zc + (size_t)srcS[base + i] * 32);
        a0 += bflo(x0); a1 += bfhi(x0);
    }
    uint xs = *(const uint*)(zc + (size_t)n * 32);
    *(float2*)(u2 + (size_t)n * D2 + c2) =
        make_float2(a0 + b0 + bflo(xs), a1 + b1 + bfhi(xs));
}

// ------ fused: relu(bn2(u2)) @ g2_W2 + b2 -> relu = h2 (W2p read transposed) -
__global__ __launch_bounds__(256) void k_m3(const float* __restrict__ u2,
                                            const float* __restrict__ sc,
                                            const float* __restrict__ sh,
                                            const float* __restrict__ W2p,  // [20][20]
                                            const float* __restrict__ b2p,
                                            float* __restrict__ h2) {
    int row = blockIdx.x * 256 + threadIdx.x;
    if (row >= NN) return;
    float ya[20];
    const float4* up = (const float4*)(u2 + (size_t)row * D2);
#pragma unroll
    for (int i = 0; i < 5; i++) {
        float4 v = up[i];
        float4 S = *(const float4*)(sc + 4 * i);
        float4 H = *(const float4*)(sh + 4 * i);
        ya[4 * i + 0] = fmaxf(v.x * S.x + H.x, 0.f);
        ya[4 * i + 1] = fmaxf(v.y * S.y + H.y, 0.f);
        ya[4 * i + 2] = fmaxf(v.z * S.z + H.z, 0.f);
        ya[4 * i + 3] = fmaxf(v.w * S.w + H.w, 0.f);
    }
    float hrow[D2];
#pragma unroll
    for (int j = 0; j < D2; j++) {
        float h = b2p[j];
#pragma unroll
        for (int k = 0; k < D2; k++) h = fmaf(ya[k], W2p[k * D2 + j], h);
        hrow[j] = fmaxf(h, 0.f);
    }
    float* hr = h2 + (size_t)row * D2;
#pragma unroll
    for (int c = 0; c < D2; c += 4) {
        float4 o; o.x = hrow[c]; o.y = hrow[c + 1]; o.z = hrow[c + 2]; o.w = hrow[c + 3];
        *(float4*)(hr + c) = o;
    }
}

// ---------------- per-graph ranges (node2graph is sorted) ----------------
__global__ void k_starts(const int* __restrict__ n2g, int* __restrict__ starts) {
    int i = blockIdx.x * 256 + threadIdx.x;
    if (i >= NN) return;
    int g = n2g[i];
    if (i == 0) {
        for (int x = 0; x <= g; x++) starts[x] = 0;
    } else {
        int gp = n2g[i - 1];
        for (int x = gp + 1; x <= g; x++) starts[x] = i;
    }
    if (i == NN - 1) {
        for (int x = g + 1; x <= NG; x++) starts[x] = NN;
    }
}

// ---- wave per graph: 60 lanes = 3 row-stripes x 20 cols, shuffle-reduce -----
__global__ __launch_bounds__(256) void k_pool(const float* __restrict__ h2,
                                              const int* __restrict__ starts,
                                              float* __restrict__ hg) {
    int wq = __builtin_amdgcn_readfirstlane(threadIdx.x >> 6);
    int l = threadIdx.x & 63;
    int g = blockIdx.x * 4 + wq;
    if (g >= NG) return;
    int s0 = starts[g], s1 = starts[g + 1];
    float a = 0.f;
    if (l < 60) {
        int rg = l / 20, c = l % 20;
        for (int n = s0 + rg; n < s1; n += 3) a += h2[(size_t)n * D2 + c];
    }
    float v1 = __shfl(a, l + 20, 64);
    float v2 = __shfl(a, l + 40, 64);
    if (l < 20) {
        float cnt = (float)(s1 - s0);
        hg[g * D2 + l] = (a + v1 + v2) / fmaxf(cnt, 1.f);
    }
}

// ---------------- a1 = kron(hg, self_feat) @ fc1_W ----------------
__global__ void k_head1(const float* __restrict__ hg, const float* __restrict__ sf,
                        const float* __restrict__ fc1W, float* __restrict__ a1) {
    int b = blockIdx.x * 8 + threadIdx.x / 32;
    int c = threadIdx.x % 32;
    if (b >= NG) return;
    const float* hgb = hg + b * D2;
    const float* sfb = sf + b * DSELF;
    float acc = 0.f;
    for (int i = 0; i < D2; i++) {
        float hi = hgb[i];
#pragma unroll
        for (int j = 0; j < DSELF; j++)
            acc += hi * sfb[j] * fc1W[(i * DSELF + j) * 32 + c];
    }
    a1[b * 32 + c] = acc;
}

// ---------------- single-block head: bn1->relu->fc2->bn2->relu->fc3 ----------
__global__ __launch_bounds__(1024) void k_head2(
    const float* __restrict__ a1, const float* __restrict__ g1,
    const float* __restrict__ be1, const float* __restrict__ fc2W,
    const float* __restrict__ g2, const float* __restrict__ be2,
    const float* __restrict__ fc3W, const float* __restrict__ fc3b,
    float* __restrict__ out) {
    int t = threadIdx.x;
    int lane = t & 63, w = t >> 6;
    __shared__ float s1[16][32], s2[16][32];
    __shared__ float sc[32], sh[32], sc2[8], sh2[8];
    float x[32];
    const float4* ap = (const float4*)(a1 + t * 32);
#pragma unroll
    for (int i = 0; i < 8; i++) {
        float4 v = ap[i];
        x[4 * i] = v.x; x[4 * i + 1] = v.y; x[4 * i + 2] = v.z; x[4 * i + 3] = v.w;
    }
#pragma unroll
    for (int c = 0; c < 32; c++) {
        float v = x[c], q = v * v;
        for (int o = 32; o > 0; o >>= 1) {
            v += __shfl_down(v, o, 64);
            q += __shfl_down(q, o, 64);
        }
        if (lane == 0) { s1[w][c] = v; s2[w][c] = q; }
    }
    __syncthreads();
    if (t < 32) {
        float s = 0.f, q = 0.f;
        for (int ww = 0; ww < 16; ww++) { s += s1[ww][t]; q += s2[ww][t]; }
        float mean = s * (1.f / NG);
        float var = q * (1.f / NG) - mean * mean;
        float inv = rsqrtf(var + BN_EPS);
        float scl = g1[t] * inv;
        sc[t] = scl;
        sh[t] = be1[t] - mean * scl;
    }
    __syncthreads();
#pragma unroll
    for (int c = 0; c < 32; c++) x[c] = fmaxf(x[c] * sc[c] + sh[c], 0.f);
    float y[8];
#pragma unroll
    for (int p = 0; p < 8; p++) {
        float a = 0.f;
#pragma unroll
        for (int c = 0; c < 32; c++) a += x[c] * fc2W[c * 8 + p];
        y[p] = a;
    }
    __syncthreads();
#pragma unroll
    for (int p = 0; p < 8; p++) {
        float v = y[p], q = v * v;
        for (int o = 32; o > 0; o >>= 1) {
            v += __shfl_down(v, o, 64);
            q += __shfl_down(q, o, 64);
        }
        if (lane == 0) { s1[w][p] = v; s2[w][p] = q; }
    }
    __syncthreads();
    if (t < 8) {
        float s = 0.f, q = 0.f;
        for (int ww = 0; ww < 16; ww++) { s += s1[ww][t]; q += s2[ww][t]; }
        float mean = s * (1.f / NG);
        float var = q * (1.f / NG) - mean * mean;
        float inv = rsqrtf(var + BN_EPS);
        float scl = g2[t] * inv;
        sc2[t] = scl;
        sh2[t] = be2[t] - mean * scl;
    }
    __syncthreads();
    float o = fc3b[0];
#pragma unroll
    for (int p = 0; p < 8; p++) {
        float yy = fmaxf(y[p] * sc2[p] + sh2[p], 0.f);
        o += yy * fc3W[p];
    }
    out[t] = o;
}

extern "C" void kernel_launch(void* const* d_in, const int* in_sizes, int n_in,
                              void* d_out, int out_size, void* d_ws, size_t ws_size,
                              hipStream_t stream) {
    const float* feat    = (const float*)d_in[0];
    const float* sf      = (const float*)d_in[1];
    const int*   esrc    = (const int*)d_in[2];
    const int*   edst    = (const int*)d_in[3];
    const int*   n2g     = (const int*)d_in[4];
    const float* g1W1    = (const float*)d_in[5];
    const float* g1gam   = (const float*)d_in[7];
    const float* g1bet   = (const float*)d_in[8];
    const float* g1W2    = (const float*)d_in[9];
    const float* g1b2    = (const float*)d_in[10];
    const float* g2W1    = (const float*)d_in[11];
    const float* g2gam   = (const float*)d_in[13];
    const float* g2bet   = (const float*)d_in[14];
    const float* g2W2    = (const float*)d_in[15];
    const float* g2b2    = (const float*)d_in[16];
    const float* fc1W    = (const float*)d_in[17];
    const float* hbn1g   = (const float*)d_in[19];
    const float* hbn1b   = (const float*)d_in[20];
    const float* fc2W    = (const float*)d_in[21];
    const float* hbn2g   = (const float*)d_in[23];
    const float* hbn2b   = (const float*)d_in[24];
    const float* fc3W    = (const float*)d_in[25];
    const float* fc3b    = (const float*)d_in[26];
    float* out = (float*)d_out;

    char* w = (char*)d_ws;
    size_t off = 0;
    auto alloc = [&](size_t bytes) -> char* {
        char* p = w + off;
        off += (bytes + 15) & ~(size_t)15;
        return p;
    };
    // region A: z1bf [100k x 128 bf16] = 25.6 MB; after k_agg1 z1bf is dead and
    // the region is re-used as z2bf (6.4 MB) + u2 (8 MB) + h2 (8 MB)
    char* regA = alloc((size_t)NN * 128 * 2);
    ushort* z1bf = (ushort*)regA;
    ushort* z2bf = (ushort*)regA;
    float*  u2   = (float*)(regA + 6400000);
    float*  h2   = (float*)(regA + 14400000);
    float* u1 = (float*)alloc((size_t)NN * D1 * 4);  // 40 MB
    int*   pbcnt = (int*)alloc((size_t)NB * NBLK * 4);  // 1.22 MB
    int*   btot  = (int*)alloc(NB * 4);
    int*   ebase = (int*)alloc((NB + 1) * 4);
    uint*  gbuf  = (uint*)alloc((size_t)NE * 4);        // 6.4 MB
    int*   deg   = (int*)alloc(NN * 4);
    int*   offs  = (int*)alloc(NN * 4);
    int*   srcS  = (int*)alloc((size_t)NE * 4);
    int*   starts= (int*)alloc((NG + 1) * 4);
    float* pb1   = (float*)alloc(500 * 200 * 4);
    float* pb2   = (float*)alloc(250 * 40 * 4);
    float* sc1   = (float*)alloc(D1 * 4);
    float* sh1   = (float*)alloc(D1 * 4);
    float* sc2   = (float*)alloc(D2 * 4);
    float* sh2   = (float*)alloc(D2 * 4);
    float* hg    = (float*)alloc(NG * D2 * 4);
    float* a1    = (float*)alloc(NG * 32 * 4);
    (void)in_sizes; (void)n_in; (void)out_size; (void)ws_size;

    k_gemm1<<<(NN + 63) / 64, 256, 0, stream>>>(feat, g1W1, z1bf);

    // deterministic CSR build (no global atomics, no memset)
    k_csrA1<<<NBLK, 256, 0, stream>>>(edst, pbcnt);
    k_csrS1<<<NB, 1024, 0, stream>>>(pbcnt, btot);
    k_csrS2<<<1, 512, 0, stream>>>(btot, ebase);
    k_csrA2<<<NBLK, 256, 0, stream>>>(esrc, edst, pbcnt, ebase, gbuf);
    k_csrB<<<NB, 256, 0, stream>>>(gbuf, ebase, deg, offs, srcS);

    k_agg1<<<(NN + 3) / 4, 256, 0, stream>>>(z1bf, offs, deg, srcS, u1);
    k_bnstat100<<<500, 256, 0, stream>>>(u1, pb1);
    k_bnfin100<<<1, 512, 0, stream>>>(pb1, g1gam, g1bet, sc1, sh1);
    k_m2<<<(NN + 63) / 64, 256, 0, stream>>>(u1, sc1, sh1, g1W2, g1b2, g2W1, z2bf);

    k_agg2<<<(NN + 24) / 25, 256, 0, stream>>>(z2bf, offs, deg, srcS, u2);
    k_bnstat20<<<250, 256, 0, stream>>>(u2, pb2);
    k_bnfin20<<<1, 512, 0, stream>>>(pb2, g2gam, g2bet, sc2, sh2);
    k_m3<<<(NN + 255) / 256, 256, 0, stream>>>(u2, sc2, sh2, g2W2, g2b2, h2);

    k_starts<<<(NN + 255) / 256, 256, 0, stream>>>(n2g, starts);
    k_pool<<<(NG + 3) / 4, 256, 0, stream>>>(h2, starts, hg);
    k_head1<<<NG / 8, 256, 0, stream>>>(hg, sf, fc1W, a1);
    k_head2<<<1, 1024, 0, stream>>>(a1, hbn1g, hbn1b, fc2W, hbn2g, hbn2b, fc3W, fc3b, out);
}